// Round 1
// baseline (695.281 us; speedup 1.0000x reference)
//
#include <hip/hip_runtime.h>
#include <math.h>

#define NUM 576
#define BSTR 50
#define CHOL_THREADS 128
#define CHOL_LDS_BYTES ((NUM * BSTR + NUM * 3) * sizeof(float))

__device__ __forceinline__ float leakyf(float v) { return v > 0.f ? v : 0.01f * v; }
__device__ __forceinline__ float sigmoidf(float v) { return 1.f / (1.f + __expf(-v)); }

// ---------------------------------------------------------------------------
// conv1: 3x3 pad1 conv on x (4,64,24,24) for BOTH branches (shared x staging),
// + leaky_relu. One block per (co, n), 576 threads (one per pixel).
// ---------------------------------------------------------------------------
__global__ __launch_bounds__(576) void conv1_kernel(
    const float* __restrict__ x,
    const float* __restrict__ wa, const float* __restrict__ ba,
    const float* __restrict__ wg, const float* __restrict__ bg,
    float* __restrict__ outa, float* __restrict__ outg)
{
  __shared__ float sx[16 * 576];
  const int co = blockIdx.x, n = blockIdx.y;
  const int tid = threadIdx.x;
  const int py = tid / 24, px = tid - py * 24;
  float acc_a = ba[co];
  float acc_g = bg[co];
  for (int c0 = 0; c0 < 64; c0 += 16) {
    __syncthreads();
#pragma unroll
    for (int k = 0; k < 16; ++k)
      sx[k * 576 + tid] = x[(n * 64 + c0 + k) * 576 + tid];
    __syncthreads();
#pragma unroll 4
    for (int k = 0; k < 16; ++k) {
      const float* wpa = wa + (co * 64 + c0 + k) * 9;
      const float* wpg = wg + (co * 64 + c0 + k) * 9;
#pragma unroll
      for (int dy = 0; dy < 3; ++dy) {
        const int yy = py + dy - 1;
        const bool oky = (unsigned)yy < 24u;
        const int iy = yy < 0 ? 0 : (yy > 23 ? 23 : yy);
#pragma unroll
        for (int dx = 0; dx < 3; ++dx) {
          const int xx = px + dx - 1;
          const bool ok = oky && ((unsigned)xx < 24u);
          const int ix = xx < 0 ? 0 : (xx > 23 ? 23 : xx);
          const float v = ok ? sx[k * 576 + iy * 24 + ix] : 0.f;
          acc_a += v * wpa[dy * 3 + dx];
          acc_g += v * wpg[dy * 3 + dx];
        }
      }
    }
  }
  const int o = (n * 64 + co) * 576 + tid;
  outa[o] = leakyf(acc_a);
  outg[o] = leakyf(acc_g);
}

// ---------------------------------------------------------------------------
// conv2: second 3x3 conv per branch. blockIdx.z selects branch.
// branch 0 (att): + sigmoid.  branch 1 (grad): identity.
// ---------------------------------------------------------------------------
__global__ __launch_bounds__(576) void conv2_kernel(
    const float* __restrict__ t1a, const float* __restrict__ t1g,
    const float* __restrict__ wa, const float* __restrict__ ba,
    const float* __restrict__ wg, const float* __restrict__ bg,
    float* __restrict__ att, float* __restrict__ grd)
{
  __shared__ float sx[16 * 576];
  const int co = blockIdx.x, n = blockIdx.y, br = blockIdx.z;
  const float* src = br ? t1g : t1a;
  const float* wp0 = br ? wg : wa;
  const float bias = br ? bg[co] : ba[co];
  float* dst = br ? grd : att;
  const int tid = threadIdx.x;
  const int py = tid / 24, px = tid - py * 24;
  float acc = bias;
  for (int c0 = 0; c0 < 64; c0 += 16) {
    __syncthreads();
#pragma unroll
    for (int k = 0; k < 16; ++k)
      sx[k * 576 + tid] = src[(n * 64 + c0 + k) * 576 + tid];
    __syncthreads();
#pragma unroll 4
    for (int k = 0; k < 16; ++k) {
      const float* wp = wp0 + (co * 64 + c0 + k) * 9;
#pragma unroll
      for (int dy = 0; dy < 3; ++dy) {
        const int yy = py + dy - 1;
        const bool oky = (unsigned)yy < 24u;
        const int iy = yy < 0 ? 0 : (yy > 23 ? 23 : yy);
#pragma unroll
        for (int dx = 0; dx < 3; ++dx) {
          const int xx = px + dx - 1;
          const bool ok = oky && ((unsigned)xx < 24u);
          const int ix = xx < 0 ? 0 : (xx > 23 ? 23 : xx);
          const float v = ok ? sx[k * 576 + iy * 24 + ix] : 0.f;
          acc += v * wp[dy * 3 + dx];
        }
      }
    }
  }
  if (br == 0) acc = sigmoidf(acc);
  dst[(n * 64 + co) * 576 + tid] = acc;
}

// ---------------------------------------------------------------------------
// SE branch: GAP -> 1x1 (64->32) leaky -> 1x1 (32->16) sigmoid.
// One block (64 threads) per n.
// ---------------------------------------------------------------------------
__global__ __launch_bounds__(64) void se_kernel(
    const float* __restrict__ x,
    const float* __restrict__ w1, const float* __restrict__ b1,
    const float* __restrict__ w2, const float* __restrict__ b2,
    float* __restrict__ sev)
{
  __shared__ float pooled[64];
  __shared__ float hid[32];
  const int n = blockIdx.x, t = threadIdx.x;
  const float4* xp4 = (const float4*)(x + (size_t)(n * 64 + t) * 576);
  float s = 0.f;
  for (int p = 0; p < 144; ++p) {
    float4 v = xp4[p];
    s += v.x + v.y + v.z + v.w;
  }
  pooled[t] = s * (1.f / 576.f);
  __syncthreads();
  if (t < 32) {
    float h = b1[t];
    for (int c = 0; c < 64; ++c) h += pooled[c] * w1[t * 64 + c];
    hid[t] = leakyf(h);
  }
  __syncthreads();
  if (t < 16) {
    float v = b2[t];
    for (int j = 0; j < 32; ++j) v += hid[j] * w2[t * 32 + j];
    sev[n * 16 + t] = sigmoidf(v);
  }
}

// ---------------------------------------------------------------------------
// Fused: assemble banded A^T A (bandwidth 48, offsets {0,1,2,24,48}) + rhs
// from att/grad, banded Cholesky (right-looking, rank-1), fused forward
// substitution, back substitution. One block per system b = n*16+g.
// Band held entirely in LDS: bnd[i*BSTR + d] = A[i][i-d].
// ---------------------------------------------------------------------------
__global__ __launch_bounds__(CHOL_THREADS) void chol_kernel(
    const float* __restrict__ att, const float* __restrict__ grd,
    float* __restrict__ sol)
{
  extern __shared__ float smem[];
  float* bnd = smem;                 // NUM * BSTR
  float* rhsL = bnd + NUM * BSTR;    // NUM
  float* yv = rhsL + NUM;            // NUM
  float* diagL = yv + NUM;           // NUM
  const int b = blockIdx.x, tid = threadIdx.x;
  const int n = b >> 4, g = b & 15;
  const float* ac = att + (size_t)(n * 64 + g * 4) * 576;
  const float* gc = grd + (size_t)(n * 64 + g * 4) * 576;

  // Static (register-resident) pair table for the trailing triangular update:
  // pairs (r1, r2), 1 <= r2 <= r1 <= 48, ordered by r1 then r2 (1176 total).
  int pr1[10], pr2[10];
#pragma unroll
  for (int q = 0; q < 10; ++q) {
    const int idx = tid + q * CHOL_THREADS;
    int r1 = 255, r2 = 0;
    if (idx < 1176) {
      r1 = (int)((sqrtf(8.f * (float)idx + 1.f) + 1.f) * 0.5f);
      while (r1 * (r1 - 1) / 2 > idx) --r1;
      while (r1 * (r1 + 1) / 2 <= idx) ++r1;
      r2 = idx - r1 * (r1 - 1) / 2 + 1;
    }
    pr1[q] = r1;
    pr2[q] = r2;
  }

  for (int i = tid; i < NUM * BSTR; i += CHOL_THREADS) bnd[i] = 0.f;
  __syncthreads();

  // Assemble. Edge (p,t) with weight s=att(p,t)^2 contributes:
  //   diag[p]+=s, diag[q]+=s, A[q][p]-=s; rhs[p]+=s*grad, rhs[q]-=s*grad.
  // Special last row: diag-only taps.
  for (int i = tid; i < NUM; i += CHOL_THREADS) {
    float diag = 1e-12f, rv = 0.f;
    float od1 = 0.f, od2 = 0.f, od24 = 0.f, od48 = 0.f;
    // t=0, d=1: valid(p) = ((p+1)%24 != 0) && (p+1 < NUM)
    if (((i + 1) % 24 != 0) && (i + 1 < NUM)) {
      float a0 = ac[0 * 576 + i]; float s = a0 * a0;
      diag += s; rv += s * gc[0 * 576 + i];
    }
    if (i - 1 >= 0 && (i % 24 != 0)) {  // p=i-1: (p+1)%24 = i%24; p+1=i<NUM always
      float a0 = ac[0 * 576 + (i - 1)]; float s = a0 * a0;
      diag += s; rv -= s * gc[0 * 576 + (i - 1)]; od1 = -s;
    }
    // t=1, d=24: valid(p) = p+24 < NUM
    if (i + 24 < NUM) {
      float a1 = ac[1 * 576 + i]; float s = a1 * a1;
      diag += s; rv += s * gc[1 * 576 + i];
    }
    if (i - 24 >= 0) {
      float a1 = ac[1 * 576 + (i - 24)]; float s = a1 * a1;
      diag += s; rv -= s * gc[1 * 576 + (i - 24)]; od24 = -s;
    }
    // t=2, d=2: valid(p) = ((p+2)%24 != 0) && (p+2 < NUM)
    if (((i + 2) % 24 != 0) && (i + 2 < NUM)) {
      float a2 = ac[2 * 576 + i]; float s = a2 * a2;
      diag += s; rv += s * gc[2 * 576 + i];
    }
    if (i - 2 >= 0 && (i % 24 != 0)) {  // p=i-2: (p+2)%24 = i%24; p+2=i<NUM always
      float a2 = ac[2 * 576 + (i - 2)]; float s = a2 * a2;
      diag += s; rv -= s * gc[2 * 576 + (i - 2)]; od2 = -s;
    }
    // t=3, d=48: valid(p) = p+48 < NUM
    if (i + 48 < NUM) {
      float a3 = ac[3 * 576 + i]; float s = a3 * a3;
      diag += s; rv += s * gc[3 * 576 + i];
    }
    if (i - 48 >= 0) {
      float a3 = ac[3 * 576 + (i - 48)]; float s = a3 * a3;
      diag += s; rv -= s * gc[3 * 576 + (i - 48)]; od48 = -s;
    }
    if (i == NUM - 1) {  // a[-1, t, -1] = 1 for all taps (diag-only)
#pragma unroll
      for (int t = 0; t < 4; ++t) {
        float a = ac[t * 576 + (NUM - 1)]; float s = a * a;
        diag += s; rv += s * gc[t * 576 + (NUM - 1)];
      }
    }
    bnd[i * BSTR + 0] = diag;
    bnd[i * BSTR + 1] = od1;
    bnd[i * BSTR + 2] = od2;
    bnd[i * BSTR + 24] = od24;
    bnd[i * BSTR + 48] = od48;
    rhsL[i] = rv;
  }
  __syncthreads();

  // Factorization + fused forward substitution (L y = rhs).
  for (int j = 0; j < NUM; ++j) {
    const int R = (NUM - 1 - j) < 48 ? (NUM - 1 - j) : 48;
    const float d = sqrtf(bnd[j * BSTR]);
    const float rd = 1.f / d;
    const float yj = rhsL[j] * rd;
    if (tid == 0) { diagL[j] = d; yv[j] = yj; }
    if (tid >= 1 && tid <= R) {
      const float l = bnd[(j + tid) * BSTR + tid] * rd;
      bnd[(j + tid) * BSTR + tid] = l;
      rhsL[j + tid] -= l * yj;
    }
    __syncthreads();
#pragma unroll
    for (int q = 0; q < 10; ++q) {
      const int r1 = pr1[q];
      if (r1 <= R) {
        const int r2 = pr2[q];
        const float l1 = bnd[(j + r1) * BSTR + r1];
        const float l2 = bnd[(j + r2) * BSTR + r2];
        bnd[(j + r1) * BSTR + (r1 - r2)] -= l1 * l2;
      }
    }
    __syncthreads();
  }

  // Back substitution (L^T x = y); x written straight to global.
  for (int i = NUM - 1; i >= 0; --i) {
    const float xi = yv[i] / diagL[i];
    const int Rb = i < 48 ? i : 48;
    if (tid >= 1 && tid <= Rb) yv[i - tid] -= bnd[i * BSTR + tid] * xi;
    if (tid == 0) sol[b * NUM + i] = xi;
    __syncthreads();
  }
}

// ---------------------------------------------------------------------------
// GroupNorm(1, GR) over (GR,h,w) per n + SE scale. One block per n.
// ---------------------------------------------------------------------------
__global__ __launch_bounds__(256) void gn_kernel(
    const float* __restrict__ sol, const float* __restrict__ sev,
    const float* __restrict__ gnw, const float* __restrict__ gnb,
    float* __restrict__ y)
{
  __shared__ double red[256];
  const int n = blockIdx.x, tid = threadIdx.x;
  const float* sp = sol + (size_t)n * 9216;
  double s = 0.0;
  for (int i = tid; i < 9216; i += 256) s += (double)sp[i];
  red[tid] = s;
  __syncthreads();
  for (int st = 128; st > 0; st >>= 1) {
    if (tid < st) red[tid] += red[tid + st];
    __syncthreads();
  }
  const double mu = red[0] / 9216.0;
  __syncthreads();
  double s2 = 0.0;
  for (int i = tid; i < 9216; i += 256) {
    double dd = (double)sp[i] - mu;
    s2 += dd * dd;
  }
  red[tid] = s2;
  __syncthreads();
  for (int st = 128; st > 0; st >>= 1) {
    if (tid < st) red[tid] += red[tid + st];
    __syncthreads();
  }
  const double var = red[0] / 9216.0;
  const float rstd = (float)(1.0 / sqrt(var + 1e-5));
  const float muf = (float)mu;
  for (int i = tid; i < 9216; i += 256) {
    const int gg = i / 576;
    y[(size_t)n * 9216 + i] =
        ((sp[i] - muf) * rstd * gnw[gg] + gnb[gg]) * sev[n * 16 + gg];
  }
}

// ---------------------------------------------------------------------------
// post conv: (4,16,24,24) -> (4,128,24,24), 3x3 pad1. Block per (co, n).
// ---------------------------------------------------------------------------
__global__ __launch_bounds__(576) void post_kernel(
    const float* __restrict__ y, const float* __restrict__ w,
    const float* __restrict__ bias, float* __restrict__ out)
{
  __shared__ float sy[16 * 576];
  const int co = blockIdx.x, n = blockIdx.y, tid = threadIdx.x;
#pragma unroll
  for (int k = 0; k < 16; ++k)
    sy[k * 576 + tid] = y[(size_t)(n * 16 + k) * 576 + tid];
  __syncthreads();
  const int py = tid / 24, px = tid - py * 24;
  float acc = bias[co];
#pragma unroll 4
  for (int k = 0; k < 16; ++k) {
    const float* wp = w + (co * 16 + k) * 9;
#pragma unroll
    for (int dy = 0; dy < 3; ++dy) {
      const int yy = py + dy - 1;
      const bool oky = (unsigned)yy < 24u;
      const int iy = yy < 0 ? 0 : (yy > 23 ? 23 : yy);
#pragma unroll
      for (int dx = 0; dx < 3; ++dx) {
        const int xx = px + dx - 1;
        const bool ok = oky && ((unsigned)xx < 24u);
        const int ix = xx < 0 ? 0 : (xx > 23 ? 23 : xx);
        const float v = ok ? sy[k * 576 + iy * 24 + ix] : 0.f;
        acc += v * wp[dy * 3 + dx];
      }
    }
  }
  out[(size_t)(n * 128 + co) * 576 + tid] = acc;
}

// ---------------------------------------------------------------------------
extern "C" void kernel_launch(void* const* d_in, const int* in_sizes, int n_in,
                              void* d_out, int out_size, void* d_ws, size_t ws_size,
                              hipStream_t stream) {
  const float* x       = (const float*)d_in[0];
  // d_in[1] is the dense stencil 'a' -- structure is known analytically; unused.
  const float* grad_w1 = (const float*)d_in[2];
  const float* grad_b1 = (const float*)d_in[3];
  const float* grad_w2 = (const float*)d_in[4];
  const float* grad_b2 = (const float*)d_in[5];
  const float* att_w1  = (const float*)d_in[6];
  const float* att_b1  = (const float*)d_in[7];
  const float* att_w2  = (const float*)d_in[8];
  const float* att_b2  = (const float*)d_in[9];
  const float* se_w1   = (const float*)d_in[10];
  const float* se_b1   = (const float*)d_in[11];
  const float* se_w2   = (const float*)d_in[12];
  const float* se_b2   = (const float*)d_in[13];
  const float* gn_w    = (const float*)d_in[14];
  const float* gn_b    = (const float*)d_in[15];
  const float* post_w  = (const float*)d_in[16];
  const float* post_b  = (const float*)d_in[17];
  float* out = (float*)d_out;

  float* ws  = (float*)d_ws;
  float* t1a = ws;              // 147456
  float* t1g = t1a + 147456;    // 147456
  float* att = t1g + 147456;    // 147456
  float* grd = att + 147456;    // 147456
  float* sev = grd + 147456;    // 64
  float* sol = sev + 64;        // 36864
  float* yb  = sol + 36864;     // 36864

  (void)hipFuncSetAttribute((const void*)chol_kernel,
                            hipFuncAttributeMaxDynamicSharedMemorySize,
                            (int)CHOL_LDS_BYTES);

  conv1_kernel<<<dim3(64, 4), 576, 0, stream>>>(x, att_w1, att_b1,
                                                grad_w1, grad_b1, t1a, t1g);
  se_kernel<<<4, 64, 0, stream>>>(x, se_w1, se_b1, se_w2, se_b2, sev);
  conv2_kernel<<<dim3(64, 4, 2), 576, 0, stream>>>(t1a, t1g, att_w2, att_b2,
                                                   grad_w2, grad_b2, att, grd);
  chol_kernel<<<64, CHOL_THREADS, CHOL_LDS_BYTES, stream>>>(att, grd, sol);
  gn_kernel<<<4, 256, 0, stream>>>(sol, sev, gn_w, gn_b, yb);
  post_kernel<<<dim3(128, 4), 576, 0, stream>>>(yb, post_w, post_b, out);
}

// Round 2
// 586.966 us; speedup vs baseline: 1.1845x; 1.1845x over previous
//
#include <hip/hip_runtime.h>
#include <math.h>

#define NUM 576
#define BSTR 50

// LDS layout (float indices) for chol_kernel
#define L_BND 0              // 576*50 = 28800
#define L_RHS 28800          // 576  (holds rhs, then y, consumed by back-subst)
#define L_RD  29376          // 576  (reciprocal diag of L)
#define L_XS  29952          // 576  (solution staging)
#define L_LC  30528          // 64   (lcol: scaled pivot column)
#define L_DUM 30592          // 64   (per-lane dummy sink)
#define CHOL_FLOATS 30656
#define CHOL_LDS_BYTES (CHOL_FLOATS * sizeof(float))
#define NSLOT 19             // ceil(1176 / 64)

__device__ __forceinline__ float leakyf(float v) { return v > 0.f ? v : 0.01f * v; }
__device__ __forceinline__ float sigmoidf(float v) { return 1.f / (1.f + __expf(-v)); }

// ---------------------------------------------------------------------------
// conv1: 3x3 pad1 conv on x (4,64,24,24) for BOTH branches (shared x staging),
// + leaky_relu. One block per (co, n), 576 threads (one per pixel).
// ---------------------------------------------------------------------------
__global__ __launch_bounds__(576) void conv1_kernel(
    const float* __restrict__ x,
    const float* __restrict__ wa, const float* __restrict__ ba,
    const float* __restrict__ wg, const float* __restrict__ bg,
    float* __restrict__ outa, float* __restrict__ outg)
{
  __shared__ float sx[16 * 576];
  const int co = blockIdx.x, n = blockIdx.y;
  const int tid = threadIdx.x;
  const int py = tid / 24, px = tid - py * 24;
  float acc_a = ba[co];
  float acc_g = bg[co];
  for (int c0 = 0; c0 < 64; c0 += 16) {
    __syncthreads();
#pragma unroll
    for (int k = 0; k < 16; ++k)
      sx[k * 576 + tid] = x[(n * 64 + c0 + k) * 576 + tid];
    __syncthreads();
#pragma unroll 4
    for (int k = 0; k < 16; ++k) {
      const float* wpa = wa + (co * 64 + c0 + k) * 9;
      const float* wpg = wg + (co * 64 + c0 + k) * 9;
#pragma unroll
      for (int dy = 0; dy < 3; ++dy) {
        const int yy = py + dy - 1;
        const bool oky = (unsigned)yy < 24u;
        const int iy = yy < 0 ? 0 : (yy > 23 ? 23 : yy);
#pragma unroll
        for (int dx = 0; dx < 3; ++dx) {
          const int xx = px + dx - 1;
          const bool ok = oky && ((unsigned)xx < 24u);
          const int ix = xx < 0 ? 0 : (xx > 23 ? 23 : xx);
          const float v = ok ? sx[k * 576 + iy * 24 + ix] : 0.f;
          acc_a += v * wpa[dy * 3 + dx];
          acc_g += v * wpg[dy * 3 + dx];
        }
      }
    }
  }
  const int o = (n * 64 + co) * 576 + tid;
  outa[o] = leakyf(acc_a);
  outg[o] = leakyf(acc_g);
}

// ---------------------------------------------------------------------------
// conv2: second 3x3 conv per branch. blockIdx.z selects branch.
// branch 0 (att): + sigmoid.  branch 1 (grad): identity.
// ---------------------------------------------------------------------------
__global__ __launch_bounds__(576) void conv2_kernel(
    const float* __restrict__ t1a, const float* __restrict__ t1g,
    const float* __restrict__ wa, const float* __restrict__ ba,
    const float* __restrict__ wg, const float* __restrict__ bg,
    float* __restrict__ att, float* __restrict__ grd)
{
  __shared__ float sx[16 * 576];
  const int co = blockIdx.x, n = blockIdx.y, br = blockIdx.z;
  const float* src = br ? t1g : t1a;
  const float* wp0 = br ? wg : wa;
  const float bias = br ? bg[co] : ba[co];
  float* dst = br ? grd : att;
  const int tid = threadIdx.x;
  const int py = tid / 24, px = tid - py * 24;
  float acc = bias;
  for (int c0 = 0; c0 < 64; c0 += 16) {
    __syncthreads();
#pragma unroll
    for (int k = 0; k < 16; ++k)
      sx[k * 576 + tid] = src[(n * 64 + c0 + k) * 576 + tid];
    __syncthreads();
#pragma unroll 4
    for (int k = 0; k < 16; ++k) {
      const float* wp = wp0 + (co * 64 + c0 + k) * 9;
#pragma unroll
      for (int dy = 0; dy < 3; ++dy) {
        const int yy = py + dy - 1;
        const bool oky = (unsigned)yy < 24u;
        const int iy = yy < 0 ? 0 : (yy > 23 ? 23 : yy);
#pragma unroll
        for (int dx = 0; dx < 3; ++dx) {
          const int xx = px + dx - 1;
          const bool ok = oky && ((unsigned)xx < 24u);
          const int ix = xx < 0 ? 0 : (xx > 23 ? 23 : xx);
          const float v = ok ? sx[k * 576 + iy * 24 + ix] : 0.f;
          acc += v * wp[dy * 3 + dx];
        }
      }
    }
  }
  if (br == 0) acc = sigmoidf(acc);
  dst[(n * 64 + co) * 576 + tid] = acc;
}

// ---------------------------------------------------------------------------
// SE branch: GAP -> 1x1 (64->32) leaky -> 1x1 (32->16) sigmoid.
// One block (64 threads) per n.
// ---------------------------------------------------------------------------
__global__ __launch_bounds__(64) void se_kernel(
    const float* __restrict__ x,
    const float* __restrict__ w1, const float* __restrict__ b1,
    const float* __restrict__ w2, const float* __restrict__ b2,
    float* __restrict__ sev)
{
  __shared__ float pooled[64];
  __shared__ float hid[32];
  const int n = blockIdx.x, t = threadIdx.x;
  const float4* xp4 = (const float4*)(x + (size_t)(n * 64 + t) * 576);
  float s = 0.f;
  for (int p = 0; p < 144; ++p) {
    float4 v = xp4[p];
    s += v.x + v.y + v.z + v.w;
  }
  pooled[t] = s * (1.f / 576.f);
  __syncthreads();
  if (t < 32) {
    float h = b1[t];
    for (int c = 0; c < 64; ++c) h += pooled[c] * w1[t * 64 + c];
    hid[t] = leakyf(h);
  }
  __syncthreads();
  if (t < 16) {
    float v = b2[t];
    for (int j = 0; j < 32; ++j) v += hid[j] * w2[t * 32 + j];
    sev[n * 16 + t] = sigmoidf(v);
  }
}

// ---------------------------------------------------------------------------
// Fused banded Cholesky solver. One WAVE (64 threads) per system b = n*16+g.
// Band bnd[i*50+d] = A[i][i-d], offsets {0,1,2,24,48}, bandwidth 48.
// Branch-free ILP-batched rank-1 update: 19 pair-slots per lane, inactive
// slots redirected to a per-lane dummy LDS word (no divergence).
// ---------------------------------------------------------------------------
__global__ __launch_bounds__(64) void chol_kernel(
    const float* __restrict__ att, const float* __restrict__ grd,
    float* __restrict__ sol)
{
  extern __shared__ float S[];
  const int b = blockIdx.x, tid = threadIdx.x;
  const int n = b >> 4, g = b & 15;
  const float* ac = att + (size_t)(n * 64 + g * 4) * 576;
  const float* gc = grd + (size_t)(n * 64 + g * 4) * 576;
  const int dum = L_DUM + tid;

  // --- pair table: pairs (r1,r2), 1<=r2<=r1<=48, idx = tid + 64q.
  // Loop-invariant per-slot data: lcol read offsets (constant), band-offset
  // stride term s1 = 51*r1 - r2 (target = j*50 + s1), activity key r1.
  int a1o[NSLOT], a2o[NSLOT], s1c[NSLOT], r1c[NSLOT];
#pragma unroll
  for (int q = 0; q < NSLOT; ++q) {
    const int idx = tid + q * 64;
    int r1 = (int)((sqrtf(8.f * (float)idx + 1.f) + 1.f) * 0.5f);
    while (r1 * (r1 - 1) / 2 > idx) --r1;
    while (r1 * (r1 + 1) / 2 <= idx) ++r1;
    int r2 = idx - r1 * (r1 - 1) / 2 + 1;
    const bool ok = idx < 1176;
    r1c[q] = ok ? r1 : 63;         // 63 > 48 -> permanently inactive sentinel
    a1o[q] = L_LC + (ok ? r1 : 63);
    a2o[q] = L_LC + (ok ? r2 : 0);
    s1c[q] = 51 * r1 - r2;
  }

  // --- zero init band + lcol + dummy
  for (int i = tid; i < NUM * BSTR; i += 64) S[L_BND + i] = 0.f;
  S[L_LC + tid] = 0.f;
  S[L_DUM + tid] = 0.f;
  __syncthreads();

  // --- assemble band + rhs (same math as verified round-1 kernel)
  for (int i = tid; i < NUM; i += 64) {
    float diag = 1e-12f, rv = 0.f;
    float od1 = 0.f, od2 = 0.f, od24 = 0.f, od48 = 0.f;
    if (((i + 1) % 24 != 0) && (i + 1 < NUM)) {
      float a0 = ac[0 * 576 + i]; float s = a0 * a0;
      diag += s; rv += s * gc[0 * 576 + i];
    }
    if (i - 1 >= 0 && (i % 24 != 0)) {
      float a0 = ac[0 * 576 + (i - 1)]; float s = a0 * a0;
      diag += s; rv -= s * gc[0 * 576 + (i - 1)]; od1 = -s;
    }
    if (i + 24 < NUM) {
      float a1 = ac[1 * 576 + i]; float s = a1 * a1;
      diag += s; rv += s * gc[1 * 576 + i];
    }
    if (i - 24 >= 0) {
      float a1 = ac[1 * 576 + (i - 24)]; float s = a1 * a1;
      diag += s; rv -= s * gc[1 * 576 + (i - 24)]; od24 = -s;
    }
    if (((i + 2) % 24 != 0) && (i + 2 < NUM)) {
      float a2 = ac[2 * 576 + i]; float s = a2 * a2;
      diag += s; rv += s * gc[2 * 576 + i];
    }
    if (i - 2 >= 0 && (i % 24 != 0)) {
      float a2 = ac[2 * 576 + (i - 2)]; float s = a2 * a2;
      diag += s; rv -= s * gc[2 * 576 + (i - 2)]; od2 = -s;
    }
    if (i + 48 < NUM) {
      float a3 = ac[3 * 576 + i]; float s = a3 * a3;
      diag += s; rv += s * gc[3 * 576 + i];
    }
    if (i - 48 >= 0) {
      float a3 = ac[3 * 576 + (i - 48)]; float s = a3 * a3;
      diag += s; rv -= s * gc[3 * 576 + (i - 48)]; od48 = -s;
    }
    if (i == NUM - 1) {
#pragma unroll
      for (int t = 0; t < 4; ++t) {
        float a = ac[t * 576 + (NUM - 1)]; float s = a * a;
        diag += s; rv += s * gc[t * 576 + (NUM - 1)];
      }
    }
    S[L_BND + i * BSTR + 0] = diag;
    S[L_BND + i * BSTR + 1] = od1;
    S[L_BND + i * BSTR + 2] = od2;
    S[L_BND + i * BSTR + 24] = od24;
    S[L_BND + i * BSTR + 48] = od48;
    S[L_RHS + i] = rv;
  }

  // --- factorization + fused forward substitution
  for (int j = 0; j < NUM; ++j) {
    __syncthreads();
    const int R = (NUM - 1 - j) < 48 ? (NUM - 1 - j) : 48;
    const int base = L_BND + j * BSTR;
    // pivot (uniform broadcast read)
    const float d = sqrtf(S[base]);
    const float rd = 1.f / d;
    const float yj = S[L_RHS + j] * rd;
    S[L_RD + j] = rd;       // all lanes, same value
    S[L_RHS + j] = yj;      // y_j
    // scale column + forward-substitution update (branch-free)
    {
      const int t = tid;
      const bool act = (t >= 1) & (t <= R);
      const int bo = act ? (base + 51 * t) : dum;   // (j+t)*50 + t
      const float l = S[bo] * rd;
      S[bo] = l;
      S[act ? (L_LC + t) : dum] = l;
      const int ro = act ? (L_RHS + j + t) : dum;
      S[ro] = S[ro] - l * yj;
    }
    __syncthreads();
    // rank-1 trailing update, phase-separated for ILP
    int ta[NSLOT];
    float a1[NSLOT], a2[NSLOT], tv[NSLOT];
#pragma unroll
    for (int q = 0; q < NSLOT; ++q)
      ta[q] = (r1c[q] <= R) ? (base + s1c[q]) : dum;
#pragma unroll
    for (int q = 0; q < NSLOT; ++q) a1[q] = S[a1o[q]];
#pragma unroll
    for (int q = 0; q < NSLOT; ++q) a2[q] = S[a2o[q]];
#pragma unroll
    for (int q = 0; q < NSLOT; ++q) tv[q] = S[ta[q]];
#pragma unroll
    for (int q = 0; q < NSLOT; ++q) S[ta[q]] = tv[q] - a1[q] * a2[q];
  }

  // --- back substitution (L^T x = y), solution staged in LDS
  for (int i = NUM - 1; i >= 0; --i) {
    __syncthreads();
    const float xi = S[L_RHS + i] * S[L_RD + i];
    S[L_XS + i] = xi;  // all lanes, same value
    const int Rb = i < 48 ? i : 48;
    const int t = tid;
    const bool act = (t >= 1) & (t <= Rb);
    const float lv = S[act ? (L_BND + i * BSTR + t) : dum];
    const int yo = act ? (L_RHS + i - t) : dum;
    S[yo] = S[yo] - lv * xi;
  }
  __syncthreads();
  for (int i = tid; i < NUM; i += 64) sol[(size_t)b * NUM + i] = S[L_XS + i];
}

// ---------------------------------------------------------------------------
// GroupNorm(1, GR) over (GR,h,w) per n + SE scale. One block per n.
// ---------------------------------------------------------------------------
__global__ __launch_bounds__(256) void gn_kernel(
    const float* __restrict__ sol, const float* __restrict__ sev,
    const float* __restrict__ gnw, const float* __restrict__ gnb,
    float* __restrict__ y)
{
  __shared__ double red[256];
  const int n = blockIdx.x, tid = threadIdx.x;
  const float* sp = sol + (size_t)n * 9216;
  double s = 0.0;
  for (int i = tid; i < 9216; i += 256) s += (double)sp[i];
  red[tid] = s;
  __syncthreads();
  for (int st = 128; st > 0; st >>= 1) {
    if (tid < st) red[tid] += red[tid + st];
    __syncthreads();
  }
  const double mu = red[0] / 9216.0;
  __syncthreads();
  double s2 = 0.0;
  for (int i = tid; i < 9216; i += 256) {
    double dd = (double)sp[i] - mu;
    s2 += dd * dd;
  }
  red[tid] = s2;
  __syncthreads();
  for (int st = 128; st > 0; st >>= 1) {
    if (tid < st) red[tid] += red[tid + st];
    __syncthreads();
  }
  const double var = red[0] / 9216.0;
  const float rstd = (float)(1.0 / sqrt(var + 1e-5));
  const float muf = (float)mu;
  for (int i = tid; i < 9216; i += 256) {
    const int gg = i / 576;
    y[(size_t)n * 9216 + i] =
        ((sp[i] - muf) * rstd * gnw[gg] + gnb[gg]) * sev[n * 16 + gg];
  }
}

// ---------------------------------------------------------------------------
// post conv: (4,16,24,24) -> (4,128,24,24), 3x3 pad1. Block per (co, n).
// ---------------------------------------------------------------------------
__global__ __launch_bounds__(576) void post_kernel(
    const float* __restrict__ y, const float* __restrict__ w,
    const float* __restrict__ bias, float* __restrict__ out)
{
  __shared__ float sy[16 * 576];
  const int co = blockIdx.x, n = blockIdx.y, tid = threadIdx.x;
#pragma unroll
  for (int k = 0; k < 16; ++k)
    sy[k * 576 + tid] = y[(size_t)(n * 16 + k) * 576 + tid];
  __syncthreads();
  const int py = tid / 24, px = tid - py * 24;
  float acc = bias[co];
#pragma unroll 4
  for (int k = 0; k < 16; ++k) {
    const float* wp = w + (co * 16 + k) * 9;
#pragma unroll
    for (int dy = 0; dy < 3; ++dy) {
      const int yy = py + dy - 1;
      const bool oky = (unsigned)yy < 24u;
      const int iy = yy < 0 ? 0 : (yy > 23 ? 23 : yy);
#pragma unroll
      for (int dx = 0; dx < 3; ++dx) {
        const int xx = px + dx - 1;
        const bool ok = oky && ((unsigned)xx < 24u);
        const int ix = xx < 0 ? 0 : (xx > 23 ? 23 : xx);
        const float v = ok ? sy[k * 576 + iy * 24 + ix] : 0.f;
        acc += v * wp[dy * 3 + dx];
      }
    }
  }
  out[(size_t)(n * 128 + co) * 576 + tid] = acc;
}

// ---------------------------------------------------------------------------
extern "C" void kernel_launch(void* const* d_in, const int* in_sizes, int n_in,
                              void* d_out, int out_size, void* d_ws, size_t ws_size,
                              hipStream_t stream) {
  const float* x       = (const float*)d_in[0];
  const float* grad_w1 = (const float*)d_in[2];
  const float* grad_b1 = (const float*)d_in[3];
  const float* grad_w2 = (const float*)d_in[4];
  const float* grad_b2 = (const float*)d_in[5];
  const float* att_w1  = (const float*)d_in[6];
  const float* att_b1  = (const float*)d_in[7];
  const float* att_w2  = (const float*)d_in[8];
  const float* att_b2  = (const float*)d_in[9];
  const float* se_w1   = (const float*)d_in[10];
  const float* se_b1   = (const float*)d_in[11];
  const float* se_w2   = (const float*)d_in[12];
  const float* se_b2   = (const float*)d_in[13];
  const float* gn_w    = (const float*)d_in[14];
  const float* gn_b    = (const float*)d_in[15];
  const float* post_w  = (const float*)d_in[16];
  const float* post_b  = (const float*)d_in[17];
  float* out = (float*)d_out;

  float* ws  = (float*)d_ws;
  float* t1a = ws;              // 147456
  float* t1g = t1a + 147456;    // 147456
  float* att = t1g + 147456;    // 147456
  float* grd = att + 147456;    // 147456
  float* sev = grd + 147456;    // 64
  float* sol = sev + 64;        // 36864
  float* yb  = sol + 36864;     // 36864

  (void)hipFuncSetAttribute((const void*)chol_kernel,
                            hipFuncAttributeMaxDynamicSharedMemorySize,
                            (int)CHOL_LDS_BYTES);

  conv1_kernel<<<dim3(64, 4), 576, 0, stream>>>(x, att_w1, att_b1,
                                                grad_w1, grad_b1, t1a, t1g);
  se_kernel<<<4, 64, 0, stream>>>(x, se_w1, se_b1, se_w2, se_b2, sev);
  conv2_kernel<<<dim3(64, 4, 2), 576, 0, stream>>>(t1a, t1g, att_w2, att_b2,
                                                   grad_w2, grad_b2, att, grd);
  chol_kernel<<<64, 64, CHOL_LDS_BYTES, stream>>>(att, grd, sol);
  gn_kernel<<<4, 256, 0, stream>>>(sol, sev, gn_w, gn_b, yb);
  post_kernel<<<dim3(128, 4), 576, 0, stream>>>(yb, post_w, post_b, out);
}

// Round 3
// 315.602 us; speedup vs baseline: 2.2030x; 1.8598x over previous
//
#include <hip/hip_runtime.h>
#include <math.h>

#define NUM 576
#define BSTR 50

// LDS float-index layout for chol_kernel
#define L_BND 0        // 28800 : band, bnd[i*50+d] = A[i][i-d]
#define L_RHS 28800    // 576   : rhs -> y -> back-subst partials
#define L_RD  29376    // 576   : 1/L[j][j]
#define L_XS  29952    // 576   : solution staging
#define L_LC  30528    // 64    : scaled pivot column j   (LC[0] stays 0 = zero slot)
#define L_LC1 30592    // 64    : scaled pivot column j+1 (LC1[0] stays 0)
#define L_DUM 30656    // 256   : per-lane dummy sink
#define CHOL_FLOATS 30912
#define CHOL_LDS_BYTES (CHOL_FLOATS * sizeof(float))
#define NSLOT 5
#define CTH 256

__device__ __forceinline__ float leakyf(float v) { return v > 0.f ? v : 0.01f * v; }
__device__ __forceinline__ float sigmoidf(float v) { return 1.f / (1.f + __expf(-v)); }

// ---------------------------------------------------------------------------
// conv1: 3x3 pad1 conv on x (4,64,24,24) for BOTH branches, + leaky_relu.
// ---------------------------------------------------------------------------
__global__ __launch_bounds__(576) void conv1_kernel(
    const float* __restrict__ x,
    const float* __restrict__ wa, const float* __restrict__ ba,
    const float* __restrict__ wg, const float* __restrict__ bg,
    float* __restrict__ outa, float* __restrict__ outg)
{
  __shared__ float sx[16 * 576];
  const int co = blockIdx.x, n = blockIdx.y;
  const int tid = threadIdx.x;
  const int py = tid / 24, px = tid - py * 24;
  float acc_a = ba[co];
  float acc_g = bg[co];
  for (int c0 = 0; c0 < 64; c0 += 16) {
    __syncthreads();
#pragma unroll
    for (int k = 0; k < 16; ++k)
      sx[k * 576 + tid] = x[(n * 64 + c0 + k) * 576 + tid];
    __syncthreads();
#pragma unroll 4
    for (int k = 0; k < 16; ++k) {
      const float* wpa = wa + (co * 64 + c0 + k) * 9;
      const float* wpg = wg + (co * 64 + c0 + k) * 9;
#pragma unroll
      for (int dy = 0; dy < 3; ++dy) {
        const int yy = py + dy - 1;
        const bool oky = (unsigned)yy < 24u;
        const int iy = yy < 0 ? 0 : (yy > 23 ? 23 : yy);
#pragma unroll
        for (int dx = 0; dx < 3; ++dx) {
          const int xx = px + dx - 1;
          const bool ok = oky && ((unsigned)xx < 24u);
          const int ix = xx < 0 ? 0 : (xx > 23 ? 23 : xx);
          const float v = ok ? sx[k * 576 + iy * 24 + ix] : 0.f;
          acc_a += v * wpa[dy * 3 + dx];
          acc_g += v * wpg[dy * 3 + dx];
        }
      }
    }
  }
  const int o = (n * 64 + co) * 576 + tid;
  outa[o] = leakyf(acc_a);
  outg[o] = leakyf(acc_g);
}

// ---------------------------------------------------------------------------
// conv2: second 3x3 conv per branch. blockIdx.z selects branch.
// ---------------------------------------------------------------------------
__global__ __launch_bounds__(576) void conv2_kernel(
    const float* __restrict__ t1a, const float* __restrict__ t1g,
    const float* __restrict__ wa, const float* __restrict__ ba,
    const float* __restrict__ wg, const float* __restrict__ bg,
    float* __restrict__ att, float* __restrict__ grd)
{
  __shared__ float sx[16 * 576];
  const int co = blockIdx.x, n = blockIdx.y, br = blockIdx.z;
  const float* src = br ? t1g : t1a;
  const float* wp0 = br ? wg : wa;
  const float bias = br ? bg[co] : ba[co];
  float* dst = br ? grd : att;
  const int tid = threadIdx.x;
  const int py = tid / 24, px = tid - py * 24;
  float acc = bias;
  for (int c0 = 0; c0 < 64; c0 += 16) {
    __syncthreads();
#pragma unroll
    for (int k = 0; k < 16; ++k)
      sx[k * 576 + tid] = src[(n * 64 + c0 + k) * 576 + tid];
    __syncthreads();
#pragma unroll 4
    for (int k = 0; k < 16; ++k) {
      const float* wp = wp0 + (co * 64 + c0 + k) * 9;
#pragma unroll
      for (int dy = 0; dy < 3; ++dy) {
        const int yy = py + dy - 1;
        const bool oky = (unsigned)yy < 24u;
        const int iy = yy < 0 ? 0 : (yy > 23 ? 23 : yy);
#pragma unroll
        for (int dx = 0; dx < 3; ++dx) {
          const int xx = px + dx - 1;
          const bool ok = oky && ((unsigned)xx < 24u);
          const int ix = xx < 0 ? 0 : (xx > 23 ? 23 : xx);
          const float v = ok ? sx[k * 576 + iy * 24 + ix] : 0.f;
          acc += v * wp[dy * 3 + dx];
        }
      }
    }
  }
  if (br == 0) acc = sigmoidf(acc);
  dst[(n * 64 + co) * 576 + tid] = acc;
}

// ---------------------------------------------------------------------------
// SE branch.
// ---------------------------------------------------------------------------
__global__ __launch_bounds__(64) void se_kernel(
    const float* __restrict__ x,
    const float* __restrict__ w1, const float* __restrict__ b1,
    const float* __restrict__ w2, const float* __restrict__ b2,
    float* __restrict__ sev)
{
  __shared__ float pooled[64];
  __shared__ float hid[32];
  const int n = blockIdx.x, t = threadIdx.x;
  const float4* xp4 = (const float4*)(x + (size_t)(n * 64 + t) * 576);
  float s = 0.f;
  for (int p = 0; p < 144; ++p) {
    float4 v = xp4[p];
    s += v.x + v.y + v.z + v.w;
  }
  pooled[t] = s * (1.f / 576.f);
  __syncthreads();
  if (t < 32) {
    float h = b1[t];
    for (int c = 0; c < 64; ++c) h += pooled[c] * w1[t * 64 + c];
    hid[t] = leakyf(h);
  }
  __syncthreads();
  if (t < 16) {
    float v = b2[t];
    for (int j = 0; j < 32; ++j) v += hid[j] * w2[t * 32 + j];
    sev[n * 16 + t] = sigmoidf(v);
  }
}

// ---------------------------------------------------------------------------
// Fused banded Cholesky solver, 256 threads (4 waves) per system.
// Fused 2-pivot supersteps (288 outer steps), rank-2 trailing update on
// targets {2<=r2<=r1<=49} (col j+1 handled in scale phase), precomputed
// rsqrt pivots, 2-row back-substitution supersteps.
// ---------------------------------------------------------------------------
__global__ __launch_bounds__(CTH, 1) void chol_kernel(
    const float* __restrict__ att, const float* __restrict__ grd,
    float* __restrict__ sol)
{
  extern __shared__ float S[];
  const int b = blockIdx.x, tid = threadIdx.x;
  const int n = b >> 4, g = b & 15;
  const float* ac = att + (size_t)(n * 64 + g * 4) * 576;
  const float* gc = grd + (size_t)(n * 64 + g * 4) * 576;
  const int dum = L_DUM + tid;

  // --- packed slot tables: targets (r1,r2), 2<=r2<=r1<=49, idx=(r1-2)(r1-1)/2+(r2-2)
  // pA = r1 | (r2<<16); pB = (51*r1-r2) | ((r1-1)<<16). Sentinel: r1=0x7FFF, rest 0.
  int pA[NSLOT], pB[NSLOT];
#pragma unroll
  for (int q = 0; q < NSLOT; ++q) {
    const int idx = tid + q * CTH;
    if (idx < 1176) {
      int k = (int)((sqrtf(8.f * (float)idx + 1.f) - 1.f) * 0.5f);
      while (k * (k + 1) / 2 > idx) --k;
      while ((k + 1) * (k + 2) / 2 <= idx) ++k;
      const int r1 = k + 2;
      const int r2 = idx - k * (k + 1) / 2 + 2;
      pA[q] = r1 | (r2 << 16);
      pB[q] = (51 * r1 - r2) | ((r1 - 1) << 16);
    } else {
      pA[q] = 0x7FFF;
      pB[q] = 0;
    }
  }

  // --- zero init
  for (int i = tid; i < NUM * BSTR; i += CTH) S[L_BND + i] = 0.f;
  if (tid < 64) { S[L_LC + tid] = 0.f; S[L_LC1 + tid] = 0.f; }
  S[L_DUM + tid] = 0.f;
  __syncthreads();

  // --- assemble band + rhs (verified math) + seed rd[0]
  for (int i = tid; i < NUM; i += CTH) {
    float diag = 1e-12f, rv = 0.f;
    float od1 = 0.f, od2 = 0.f, od24 = 0.f, od48 = 0.f;
    if (((i + 1) % 24 != 0) && (i + 1 < NUM)) {
      float a0 = ac[0 * 576 + i]; float s = a0 * a0;
      diag += s; rv += s * gc[0 * 576 + i];
    }
    if (i - 1 >= 0 && (i % 24 != 0)) {
      float a0 = ac[0 * 576 + (i - 1)]; float s = a0 * a0;
      diag += s; rv -= s * gc[0 * 576 + (i - 1)]; od1 = -s;
    }
    if (i + 24 < NUM) {
      float a1 = ac[1 * 576 + i]; float s = a1 * a1;
      diag += s; rv += s * gc[1 * 576 + i];
    }
    if (i - 24 >= 0) {
      float a1 = ac[1 * 576 + (i - 24)]; float s = a1 * a1;
      diag += s; rv -= s * gc[1 * 576 + (i - 24)]; od24 = -s;
    }
    if (((i + 2) % 24 != 0) && (i + 2 < NUM)) {
      float a2 = ac[2 * 576 + i]; float s = a2 * a2;
      diag += s; rv += s * gc[2 * 576 + i];
    }
    if (i - 2 >= 0 && (i % 24 != 0)) {
      float a2 = ac[2 * 576 + (i - 2)]; float s = a2 * a2;
      diag += s; rv -= s * gc[2 * 576 + (i - 2)]; od2 = -s;
    }
    if (i + 48 < NUM) {
      float a3 = ac[3 * 576 + i]; float s = a3 * a3;
      diag += s; rv += s * gc[3 * 576 + i];
    }
    if (i - 48 >= 0) {
      float a3 = ac[3 * 576 + (i - 48)]; float s = a3 * a3;
      diag += s; rv -= s * gc[3 * 576 + (i - 48)]; od48 = -s;
    }
    if (i == NUM - 1) {
#pragma unroll
      for (int t = 0; t < 4; ++t) {
        float a = ac[t * 576 + (NUM - 1)]; float s = a * a;
        diag += s; rv += s * gc[t * 576 + (NUM - 1)];
      }
    }
    S[L_BND + i * BSTR + 0] = diag;
    S[L_BND + i * BSTR + 1] = od1;
    S[L_BND + i * BSTR + 2] = od2;
    S[L_BND + i * BSTR + 24] = od24;
    S[L_BND + i * BSTR + 48] = od48;
    S[L_RHS + i] = rv;
    if (i == 0) S[L_RD + 0] = rsqrtf(diag);
  }

  // --- factorization: 288 fused 2-pivot supersteps
  for (int j = 0; j < NUM; j += 2) {
    __syncthreads();
    const int R = (NUM - 1) - j;
    // ---- scale phase (wave 0 only): pivots j and j+1, cols, y's, rhs fwd-subst
    if (tid < 64) {
      const int t = tid;
      const int Tj = R < 48 ? R : 48;
      const int Tj1 = (R - 1) < 48 ? (R - 1) : 48;
      const float rdj = S[L_RD + j];
      const float zj = S[L_RHS + j];
      const float zj1 = S[L_RHS + j + 1];
      const float d1raw = S[L_BND + (j + 1) * BSTR];
      const bool aj = (t >= 1) & (t <= Tj);
      const bool aj1 = (t >= 1) & (t <= Tj1);
      const int cjo = aj ? (L_BND + (j + t) * BSTR + t) : (L_LC + 0);
      const int cj1o = aj1 ? (L_BND + (j + 1 + t) * BSTR + t) : (L_LC + 0);
      const float cj = S[cjo];
      const float cj1 = S[cj1o];
      const float l = cj * rdj;                    // 0 for inactive lanes
      const float l1 = __shfl(l, 1);               // L[j+1][j]
      const float d1 = d1raw - l1 * l1;
      const float rd1 = rsqrtf(d1);
      const float lnext = __shfl_down(l, 1);       // l[t+1] (0-padded)
      const float lj1 = (cj1 - lnext * l1) * rd1;  // scaled col j+1; 0 inactive
      // store L columns
      S[aj ? (L_BND + (j + t) * BSTR + t) : dum] = l;
      S[aj1 ? (L_BND + (j + 1 + t) * BSTR + t) : dum] = lj1;
      if (t >= 1) { S[L_LC + t] = l; S[L_LC1 + t] = lj1; }  // [0] stays 0
      // forward substitution for both pivots
      const float yj = zj * rdj;
      const float yj1 = (zj1 - l1 * yj) * rd1;
      const bool am = (t >= 1) & (j + 1 + t <= NUM - 1);
      const int ro = am ? (L_RHS + j + 1 + t) : dum;
      S[ro] = S[ro] - (lnext * yj + lj1 * yj1);
      if (t == 0) {
        S[L_RHS + j] = yj;
        S[L_RHS + j + 1] = yj1;
        S[L_RD + j + 1] = rd1;
      }
    }
    __syncthreads();
    // ---- rank-2 trailing update (all 4 waves), phase-separated for ILP
    int to[NSLOT];
    float v1[NSLOT], v2[NSLOT], w1[NSLOT], w2[NSLOT], tv[NSLOT];
    int act0 = 0;
#pragma unroll
    for (int q = 0; q < NSLOT; ++q) {
      const int A = pA[q], B = pB[q];
      const int r1 = A & 0xffff, r2 = A >> 16;
      const int s1 = B & 0xffff, r1m = B >> 16;
      const bool act = (r1 <= R);
      if (q == 0) act0 = act ? 1 : 0;
      v1[q] = S[L_LC + ((r1 <= 48) ? r1 : 0)];
      v2[q] = S[L_LC + r2];
      w1[q] = S[L_LC1 + r1m];
      w2[q] = S[L_LC1 + ((r2 > 0) ? (r2 - 1) : 0)];
      to[q] = act ? (L_BND + j * BSTR + s1) : dum;
    }
#pragma unroll
    for (int q = 0; q < NSLOT; ++q) tv[q] = S[to[q]];
#pragma unroll
    for (int q = 0; q < NSLOT; ++q) {
      const float nv = tv[q] - v1[q] * v2[q] - w1[q] * w2[q];
      S[to[q]] = nv;
      if (q == 0 && tid == 0 && act0)   // slot (2,2): d_{j+2} final -> precompute rd
        S[L_RD + j + 2] = rsqrtf(nv);
    }
  }

  // --- back substitution: 288 2-row supersteps (wave 0 only)
  for (int i = NUM - 1; i >= 1; i -= 2) {
    __syncthreads();
    if (tid < 64) {
      const int t = tid;
      const float zi = S[L_RHS + i], rdi = S[L_RD + i];
      const float zm = S[L_RHS + i - 1], rdm = S[L_RD + i - 1];
      const float lv1 = S[L_BND + i * BSTR + 1];
      const float xi = zi * rdi;
      const float xm = (zm - lv1 * xi) * rdm;
      const bool av = (t >= 1) & (t <= 47);
      const bool aw = (t >= 1) & (t <= 48);
      const bool am = aw & (i - 1 - t >= 0);
      const float lv = S[av ? (L_BND + i * BSTR + t + 1) : (L_LC + 0)];
      const float lw = S[aw ? (L_BND + (i - 1) * BSTR + t) : (L_LC + 0)];
      const int ro = am ? (L_RHS + i - 1 - t) : dum;
      S[ro] = S[ro] - lv * xi - lw * xm;
      if (t == 0) { S[L_XS + i] = xi; S[L_XS + i - 1] = xm; }
    }
  }
  __syncthreads();
  for (int i = tid; i < NUM; i += CTH) sol[(size_t)b * NUM + i] = S[L_XS + i];
}

// ---------------------------------------------------------------------------
// GroupNorm(1, GR) + SE scale.
// ---------------------------------------------------------------------------
__global__ __launch_bounds__(256) void gn_kernel(
    const float* __restrict__ sol, const float* __restrict__ sev,
    const float* __restrict__ gnw, const float* __restrict__ gnb,
    float* __restrict__ y)
{
  __shared__ double red[256];
  const int n = blockIdx.x, tid = threadIdx.x;
  const float* sp = sol + (size_t)n * 9216;
  double s = 0.0;
  for (int i = tid; i < 9216; i += 256) s += (double)sp[i];
  red[tid] = s;
  __syncthreads();
  for (int st = 128; st > 0; st >>= 1) {
    if (tid < st) red[tid] += red[tid + st];
    __syncthreads();
  }
  const double mu = red[0] / 9216.0;
  __syncthreads();
  double s2 = 0.0;
  for (int i = tid; i < 9216; i += 256) {
    double dd = (double)sp[i] - mu;
    s2 += dd * dd;
  }
  red[tid] = s2;
  __syncthreads();
  for (int st = 128; st > 0; st >>= 1) {
    if (tid < st) red[tid] += red[tid + st];
    __syncthreads();
  }
  const double var = red[0] / 9216.0;
  const float rstd = (float)(1.0 / sqrt(var + 1e-5));
  const float muf = (float)mu;
  for (int i = tid; i < 9216; i += 256) {
    const int gg = i / 576;
    y[(size_t)n * 9216 + i] =
        ((sp[i] - muf) * rstd * gnw[gg] + gnb[gg]) * sev[n * 16 + gg];
  }
}

// ---------------------------------------------------------------------------
// post conv: (4,16,24,24) -> (4,128,24,24), 3x3 pad1.
// ---------------------------------------------------------------------------
__global__ __launch_bounds__(576) void post_kernel(
    const float* __restrict__ y, const float* __restrict__ w,
    const float* __restrict__ bias, float* __restrict__ out)
{
  __shared__ float sy[16 * 576];
  const int co = blockIdx.x, n = blockIdx.y, tid = threadIdx.x;
#pragma unroll
  for (int k = 0; k < 16; ++k)
    sy[k * 576 + tid] = y[(size_t)(n * 16 + k) * 576 + tid];
  __syncthreads();
  const int py = tid / 24, px = tid - py * 24;
  float acc = bias[co];
#pragma unroll 4
  for (int k = 0; k < 16; ++k) {
    const float* wp = w + (co * 16 + k) * 9;
#pragma unroll
    for (int dy = 0; dy < 3; ++dy) {
      const int yy = py + dy - 1;
      const bool oky = (unsigned)yy < 24u;
      const int iy = yy < 0 ? 0 : (yy > 23 ? 23 : yy);
#pragma unroll
      for (int dx = 0; dx < 3; ++dx) {
        const int xx = px + dx - 1;
        const bool ok = oky && ((unsigned)xx < 24u);
        const int ix = xx < 0 ? 0 : (xx > 23 ? 23 : xx);
        const float v = ok ? sy[k * 576 + iy * 24 + ix] : 0.f;
        acc += v * wp[dy * 3 + dx];
      }
    }
  }
  out[(size_t)(n * 128 + co) * 576 + tid] = acc;
}

// ---------------------------------------------------------------------------
extern "C" void kernel_launch(void* const* d_in, const int* in_sizes, int n_in,
                              void* d_out, int out_size, void* d_ws, size_t ws_size,
                              hipStream_t stream) {
  const float* x       = (const float*)d_in[0];
  const float* grad_w1 = (const float*)d_in[2];
  const float* grad_b1 = (const float*)d_in[3];
  const float* grad_w2 = (const float*)d_in[4];
  const float* grad_b2 = (const float*)d_in[5];
  const float* att_w1  = (const float*)d_in[6];
  const float* att_b1  = (const float*)d_in[7];
  const float* att_w2  = (const float*)d_in[8];
  const float* att_b2  = (const float*)d_in[9];
  const float* se_w1   = (const float*)d_in[10];
  const float* se_b1   = (const float*)d_in[11];
  const float* se_w2   = (const float*)d_in[12];
  const float* se_b2   = (const float*)d_in[13];
  const float* gn_w    = (const float*)d_in[14];
  const float* gn_b    = (const float*)d_in[15];
  const float* post_w  = (const float*)d_in[16];
  const float* post_b  = (const float*)d_in[17];
  float* out = (float*)d_out;

  float* ws  = (float*)d_ws;
  float* t1a = ws;              // 147456
  float* t1g = t1a + 147456;    // 147456
  float* att = t1g + 147456;    // 147456
  float* grd = att + 147456;    // 147456
  float* sev = grd + 147456;    // 64
  float* sol = sev + 64;        // 36864
  float* yb  = sol + 36864;     // 36864

  (void)hipFuncSetAttribute((const void*)chol_kernel,
                            hipFuncAttributeMaxDynamicSharedMemorySize,
                            (int)CHOL_LDS_BYTES);

  conv1_kernel<<<dim3(64, 4), 576, 0, stream>>>(x, att_w1, att_b1,
                                                grad_w1, grad_b1, t1a, t1g);
  se_kernel<<<4, 64, 0, stream>>>(x, se_w1, se_b1, se_w2, se_b2, sev);
  conv2_kernel<<<dim3(64, 4, 2), 576, 0, stream>>>(t1a, t1g, att_w2, att_b2,
                                                   grad_w2, grad_b2, att, grd);
  chol_kernel<<<64, CTH, CHOL_LDS_BYTES, stream>>>(att, grd, sol);
  gn_kernel<<<4, 256, 0, stream>>>(sol, sev, gn_w, gn_b, yb);
  post_kernel<<<dim3(128, 4), 576, 0, stream>>>(yb, post_w, post_b, out);
}

// Round 4
// 269.881 us; speedup vs baseline: 2.5763x; 1.1694x over previous
//
#include <hip/hip_runtime.h>
#include <math.h>

#define NUM 576
#define BSTR 50
#define CTH 256
#define NSLOT 5
// dynamic LDS: band (576*50) + 256-float dummy sink
#define CHOL_LDS_BYTES ((NUM * BSTR + CTH) * sizeof(float))

__device__ __forceinline__ float leakyf(float v) { return v > 0.f ? v : 0.01f * v; }
__device__ __forceinline__ float sigmoidf(float v) { return 1.f / (1.f + __expf(-v)); }

// ---------------------------------------------------------------------------
// conv1: 3x3 pad1 conv on x (4,64,24,24) for BOTH branches, + leaky_relu.
// ---------------------------------------------------------------------------
__global__ __launch_bounds__(576) void conv1_kernel(
    const float* __restrict__ x,
    const float* __restrict__ wa, const float* __restrict__ ba,
    const float* __restrict__ wg, const float* __restrict__ bg,
    float* __restrict__ outa, float* __restrict__ outg)
{
  __shared__ float sx[16 * 576];
  const int co = blockIdx.x, n = blockIdx.y;
  const int tid = threadIdx.x;
  const int py = tid / 24, px = tid - py * 24;
  float acc_a = ba[co];
  float acc_g = bg[co];
  for (int c0 = 0; c0 < 64; c0 += 16) {
    __syncthreads();
#pragma unroll
    for (int k = 0; k < 16; ++k)
      sx[k * 576 + tid] = x[(n * 64 + c0 + k) * 576 + tid];
    __syncthreads();
#pragma unroll 4
    for (int k = 0; k < 16; ++k) {
      const float* wpa = wa + (co * 64 + c0 + k) * 9;
      const float* wpg = wg + (co * 64 + c0 + k) * 9;
#pragma unroll
      for (int dy = 0; dy < 3; ++dy) {
        const int yy = py + dy - 1;
        const bool oky = (unsigned)yy < 24u;
        const int iy = yy < 0 ? 0 : (yy > 23 ? 23 : yy);
#pragma unroll
        for (int dx = 0; dx < 3; ++dx) {
          const int xx = px + dx - 1;
          const bool ok = oky && ((unsigned)xx < 24u);
          const int ix = xx < 0 ? 0 : (xx > 23 ? 23 : xx);
          const float v = ok ? sx[k * 576 + iy * 24 + ix] : 0.f;
          acc_a += v * wpa[dy * 3 + dx];
          acc_g += v * wpg[dy * 3 + dx];
        }
      }
    }
  }
  const int o = (n * 64 + co) * 576 + tid;
  outa[o] = leakyf(acc_a);
  outg[o] = leakyf(acc_g);
}

// ---------------------------------------------------------------------------
// conv2: second 3x3 conv per branch. blockIdx.z selects branch.
// ---------------------------------------------------------------------------
__global__ __launch_bounds__(576) void conv2_kernel(
    const float* __restrict__ t1a, const float* __restrict__ t1g,
    const float* __restrict__ wa, const float* __restrict__ ba,
    const float* __restrict__ wg, const float* __restrict__ bg,
    float* __restrict__ att, float* __restrict__ grd)
{
  __shared__ float sx[16 * 576];
  const int co = blockIdx.x, n = blockIdx.y, br = blockIdx.z;
  const float* src = br ? t1g : t1a;
  const float* wp0 = br ? wg : wa;
  const float bias = br ? bg[co] : ba[co];
  float* dst = br ? grd : att;
  const int tid = threadIdx.x;
  const int py = tid / 24, px = tid - py * 24;
  float acc = bias;
  for (int c0 = 0; c0 < 64; c0 += 16) {
    __syncthreads();
#pragma unroll
    for (int k = 0; k < 16; ++k)
      sx[k * 576 + tid] = src[(n * 64 + c0 + k) * 576 + tid];
    __syncthreads();
#pragma unroll 4
    for (int k = 0; k < 16; ++k) {
      const float* wp = wp0 + (co * 64 + c0 + k) * 9;
#pragma unroll
      for (int dy = 0; dy < 3; ++dy) {
        const int yy = py + dy - 1;
        const bool oky = (unsigned)yy < 24u;
        const int iy = yy < 0 ? 0 : (yy > 23 ? 23 : yy);
#pragma unroll
        for (int dx = 0; dx < 3; ++dx) {
          const int xx = px + dx - 1;
          const bool ok = oky && ((unsigned)xx < 24u);
          const int ix = xx < 0 ? 0 : (xx > 23 ? 23 : xx);
          const float v = ok ? sx[k * 576 + iy * 24 + ix] : 0.f;
          acc += v * wp[dy * 3 + dx];
        }
      }
    }
  }
  if (br == 0) acc = sigmoidf(acc);
  dst[(n * 64 + co) * 576 + tid] = acc;
}

// ---------------------------------------------------------------------------
// SE branch.
// ---------------------------------------------------------------------------
__global__ __launch_bounds__(64) void se_kernel(
    const float* __restrict__ x,
    const float* __restrict__ w1, const float* __restrict__ b1,
    const float* __restrict__ w2, const float* __restrict__ b2,
    float* __restrict__ sev)
{
  __shared__ float pooled[64];
  __shared__ float hid[32];
  const int n = blockIdx.x, t = threadIdx.x;
  const float4* xp4 = (const float4*)(x + (size_t)(n * 64 + t) * 576);
  float s = 0.f;
  for (int p = 0; p < 144; ++p) {
    float4 v = xp4[p];
    s += v.x + v.y + v.z + v.w;
  }
  pooled[t] = s * (1.f / 576.f);
  __syncthreads();
  if (t < 32) {
    float h = b1[t];
    for (int c = 0; c < 64; ++c) h += pooled[c] * w1[t * 64 + c];
    hid[t] = leakyf(h);
  }
  __syncthreads();
  if (t < 16) {
    float v = b2[t];
    for (int j = 0; j < 32; ++j) v += hid[j] * w2[t * 32 + j];
    sev[n * 16 + t] = sigmoidf(v);
  }
}

// ---------------------------------------------------------------------------
// Fused banded Cholesky solver. 256 threads (4 waves) per system.
// Rank-4 supersteps (144): wave-0 in-register 4-column micro-Cholesky
// (lane t <-> row j+t) with fused forward substitution, then rank-4
// trailing update of 1176 band targets by all 4 waves. Static __shared__
// C arrays break aliasing with the extern band so loads batch.
// Back substitution: 144 4-row supersteps, single wave, wave-synchronous.
// ---------------------------------------------------------------------------
__global__ __launch_bounds__(CTH, 1) void chol_kernel(
    const float* __restrict__ att, const float* __restrict__ grd,
    float* __restrict__ sol)
{
  extern __shared__ float S[];          // [28800] band + [256] dummy sink
  __shared__ float RHS_s[NUM];
  __shared__ float RD_s[NUM];
  __shared__ float XS_s[NUM];
  __shared__ float C0[64], C1[64], C2[64], C3[64];
  __shared__ float DUMW[64];
  const int b = blockIdx.x, tid = threadIdx.x;
  const int n = b >> 4, g = b & 15;
  const float* ac = att + (size_t)(n * 64 + g * 4) * 576;
  const float* gc = grd + (size_t)(n * 64 + g * 4) * 576;

  // --- slot table: targets (r1,r2), 4<=r2<=r1<=51; idx=(r1-4)(r1-3)/2+(r2-4)
  // enc = r1 | (r2<<6) | ((51*r1-r2)<<12). Sentinel r1=63.
  int ptab[NSLOT];
#pragma unroll
  for (int q = 0; q < NSLOT; ++q) {
    const int idx = tid + q * CTH;
    int enc = 63;
    if (idx < 1176) {
      int k = (int)((sqrtf(8.f * (float)idx + 1.f) - 1.f) * 0.5f);
      while (k * (k + 1) / 2 > idx) --k;
      while ((k + 1) * (k + 2) / 2 <= idx) ++k;
      const int r1 = k + 4;
      const int r2 = idx - k * (k + 1) / 2 + 4;
      enc = r1 | (r2 << 6) | ((51 * r1 - r2) << 12);
    }
    ptab[q] = enc;
  }

  // --- zero band
  for (int i = tid; i < NUM * BSTR; i += CTH) S[i] = 0.f;
  __syncthreads();

  // --- assemble band + rhs (verified math), seed rd[0]
  for (int i = tid; i < NUM; i += CTH) {
    float diag = 1e-12f, rv = 0.f;
    float od1 = 0.f, od2 = 0.f, od24 = 0.f, od48 = 0.f;
    if (((i + 1) % 24 != 0) && (i + 1 < NUM)) {
      float a0 = ac[0 * 576 + i]; float s = a0 * a0;
      diag += s; rv += s * gc[0 * 576 + i];
    }
    if (i - 1 >= 0 && (i % 24 != 0)) {
      float a0 = ac[0 * 576 + (i - 1)]; float s = a0 * a0;
      diag += s; rv -= s * gc[0 * 576 + (i - 1)]; od1 = -s;
    }
    if (i + 24 < NUM) {
      float a1 = ac[1 * 576 + i]; float s = a1 * a1;
      diag += s; rv += s * gc[1 * 576 + i];
    }
    if (i - 24 >= 0) {
      float a1 = ac[1 * 576 + (i - 24)]; float s = a1 * a1;
      diag += s; rv -= s * gc[1 * 576 + (i - 24)]; od24 = -s;
    }
    if (((i + 2) % 24 != 0) && (i + 2 < NUM)) {
      float a2 = ac[2 * 576 + i]; float s = a2 * a2;
      diag += s; rv += s * gc[2 * 576 + i];
    }
    if (i - 2 >= 0 && (i % 24 != 0)) {
      float a2 = ac[2 * 576 + (i - 2)]; float s = a2 * a2;
      diag += s; rv -= s * gc[2 * 576 + (i - 2)]; od2 = -s;
    }
    if (i + 48 < NUM) {
      float a3 = ac[3 * 576 + i]; float s = a3 * a3;
      diag += s; rv += s * gc[3 * 576 + i];
    }
    if (i - 48 >= 0) {
      float a3 = ac[3 * 576 + (i - 48)]; float s = a3 * a3;
      diag += s; rv -= s * gc[3 * 576 + (i - 48)]; od48 = -s;
    }
    if (i == NUM - 1) {
#pragma unroll
      for (int t = 0; t < 4; ++t) {
        float a = ac[t * 576 + (NUM - 1)]; float s = a * a;
        diag += s; rv += s * gc[t * 576 + (NUM - 1)];
      }
    }
    S[i * BSTR + 0] = diag;
    S[i * BSTR + 1] = od1;
    S[i * BSTR + 2] = od2;
    S[i * BSTR + 24] = od24;
    S[i * BSTR + 48] = od48;
    RHS_s[i] = rv;
    if (i == 0) RD_s[0] = rsqrtf(diag);
  }

  // --- factorization: 144 rank-4 supersteps
  for (int j = 0; j < NUM; j += 4) {
    __syncthreads();                       // update(j-4) complete
    // ---- scale phase: wave 0, in-register 4-col micro-Cholesky
    if (tid < 64) {
      const int t = tid;
      const int row = j + t;
      const bool rok = row < NUM;
      const int rowa = (rok ? row : (NUM - 1)) * BSTR;
      float v0 = S[rowa + (t <= 49 ? t : 49)];
      v0 = (rok && t <= 49) ? v0 : 0.f;
      float v1 = S[rowa + (t >= 1 ? (t - 1 <= 49 ? t - 1 : 49) : 0)];
      v1 = (rok && t >= 1 && t - 1 <= 49) ? v1 : 0.f;
      float v2 = S[rowa + (t >= 2 ? (t - 2 <= 49 ? t - 2 : 49) : 0)];
      v2 = (rok && t >= 2 && t - 2 <= 49) ? v2 : 0.f;
      float v3 = S[rowa + (t >= 3 ? (t - 3 <= 49 ? t - 3 : 49) : 0)];
      v3 = (rok && t >= 3 && t - 3 <= 49) ? v3 : 0.f;
      float z = RHS_s[rok ? row : (NUM - 1)];
      z = rok ? z : 0.f;
      const float zb0 = RHS_s[j], zb1 = RHS_s[j + 1];
      const float zb2 = RHS_s[j + 2], zb3 = RHS_s[j + 3];
      const float rd0 = RD_s[j];
      v0 *= rd0;
      const float l10 = __shfl(v0, 1), l20 = __shfl(v0, 2), l30 = __shfl(v0, 3);
      v1 -= v0 * l10; v2 -= v0 * l20; v3 -= v0 * l30;
      const float rd1 = rsqrtf(__shfl(v1, 1));
      v1 *= rd1;
      const float l21 = __shfl(v1, 2), l31 = __shfl(v1, 3);
      v2 -= v1 * l21; v3 -= v1 * l31;
      const float rd2 = rsqrtf(__shfl(v2, 2));
      v2 *= rd2;
      const float l32 = __shfl(v2, 3);
      v3 -= v2 * l32;
      const float rd3 = rsqrtf(__shfl(v3, 3));
      v3 *= rd3;
      // fused forward substitution
      const float y0 = zb0 * rd0;
      const float y1 = (zb1 - l10 * y0) * rd1;
      const float y2 = (zb2 - l20 * y0 - l21 * y1) * rd2;
      const float y3 = (zb3 - l30 * y0 - l31 * y1 - l32 * y2) * rd3;
      const float zn = z - (v0 * y0 + v1 * y1 + v2 * y2 + v3 * y3);
      // stores: scaled columns to band
      float* bp;
      bp = (rok && t <= 49) ? &S[row * BSTR + t] : &S[NUM * BSTR + t]; *bp = v0;
      bp = (rok && t >= 1 && t - 1 <= 49) ? &S[row * BSTR + t - 1] : &S[NUM * BSTR + t]; *bp = v1;
      bp = (rok && t >= 2 && t - 2 <= 49) ? &S[row * BSTR + t - 2] : &S[NUM * BSTR + t]; *bp = v2;
      bp = (rok && t >= 3 && t - 3 <= 49) ? &S[row * BSTR + t - 3] : &S[NUM * BSTR + t]; *bp = v3;
      C0[t] = (t > 0) ? v0 : 0.f;
      C1[t] = (t > 1) ? v1 : 0.f;
      C2[t] = (t > 2) ? v2 : 0.f;
      C3[t] = (t > 3) ? v3 : 0.f;
      if (t < 4) {
        RHS_s[row] = (t == 0) ? y0 : (t == 1) ? y1 : (t == 2) ? y2 : y3;
        RD_s[row] = (t == 0) ? rd0 : (t == 1) ? rd1 : (t == 2) ? rd2 : rd3;
      } else {
        float* rp = rok ? &RHS_s[row] : &DUMW[t & 63];
        *rp = zn;
      }
    }
    __syncthreads();                       // C arrays + columns visible
    // ---- rank-4 trailing update (all 4 waves), batched loads
    const int R = (NUM - 1) - j;
    float c0a[NSLOT], c0b[NSLOT], c1a[NSLOT], c1b[NSLOT];
    float c2a[NSLOT], c2b[NSLOT], c3a[NSLOT], c3b[NSLOT], tv[NSLOT];
    float* wp[NSLOT];
    int act0 = 0;
#pragma unroll
    for (int q = 0; q < NSLOT; ++q) {
      const int enc = ptab[q];
      const int r1 = enc & 63, r2 = (enc >> 6) & 63, s1 = enc >> 12;
      const bool act = r1 <= R;
      if (q == 0) act0 = act ? 1 : 0;
      wp[q] = act ? &S[j * BSTR + s1] : &S[NUM * BSTR + tid];
      c0a[q] = C0[r1]; c0b[q] = C0[r2];
      c1a[q] = C1[r1]; c1b[q] = C1[r2];
      c2a[q] = C2[r1]; c2b[q] = C2[r2];
      c3a[q] = C3[r1]; c3b[q] = C3[r2];
    }
#pragma unroll
    for (int q = 0; q < NSLOT; ++q) tv[q] = *(wp[q]);
#pragma unroll
    for (int q = 0; q < NSLOT; ++q) {
      const float nv = tv[q] - c0a[q] * c0b[q] - c1a[q] * c1b[q]
                             - c2a[q] * c2b[q] - c3a[q] * c3b[q];
      *(wp[q]) = nv;
      if (q == 0 && tid == 0 && act0)      // slot (4,4): d_{j+4} final
        RD_s[j + 4] = rsqrtf(nv);
    }
  }
  __syncthreads();

  // --- back substitution: 144 4-row supersteps, single wave
  if (tid < 64) {
    const int t = tid;
    for (int i = NUM - 1; i >= 3; i -= 4) {
      asm volatile("s_waitcnt lgkmcnt(0)" ::: "memory");
      const float z0 = RHS_s[i], z1 = RHS_s[i - 1];
      const float z2 = RHS_s[i - 2], z3 = RHS_s[i - 3];
      const float r0 = RD_s[i], r1 = RD_s[i - 1];
      const float r2 = RD_s[i - 2], r3 = RD_s[i - 3];
      const float b01 = S[i * BSTR + 1], b02 = S[i * BSTR + 2], b03 = S[i * BSTR + 3];
      const float b12 = S[(i - 1) * BSTR + 1], b13 = S[(i - 1) * BSTR + 2];
      const float b23 = S[(i - 2) * BSTR + 1];
      const float x0 = z0 * r0;
      const float x1 = (z1 - b01 * x0) * r1;
      const float x2 = (z2 - b02 * x0 - b12 * x1) * r2;
      const float x3 = (z3 - b03 * x0 - b13 * x1 - b23 * x2) * r3;
      const int bb = i - 4 - t;
      const bool bok = bb >= 0;
      float L0 = S[i * BSTR + (4 + t <= 49 ? 4 + t : 49)];
      L0 = (4 + t <= 49) ? L0 : 0.f;
      float L1 = S[(i - 1) * BSTR + (3 + t <= 49 ? 3 + t : 49)];
      L1 = (3 + t <= 49) ? L1 : 0.f;
      float L2 = S[(i - 2) * BSTR + (2 + t <= 49 ? 2 + t : 49)];
      L2 = (2 + t <= 49) ? L2 : 0.f;
      float L3 = S[(i - 3) * BSTR + (1 + t <= 49 ? 1 + t : 49)];
      L3 = (1 + t <= 49) ? L3 : 0.f;
      const float zb = RHS_s[bok ? bb : 0];
      const float nz = zb - (L0 * x0 + L1 * x1 + L2 * x2 + L3 * x3);
      float* rp = bok ? &RHS_s[bb] : &DUMW[t];
      *rp = nz;
      if (t < 4) XS_s[i - t] = (t == 0) ? x0 : (t == 1) ? x1 : (t == 2) ? x2 : x3;
    }
  }
  __syncthreads();
  for (int i = tid; i < NUM; i += CTH) sol[(size_t)b * NUM + i] = XS_s[i];
}

// ---------------------------------------------------------------------------
// GroupNorm(1, GR) + SE scale.
// ---------------------------------------------------------------------------
__global__ __launch_bounds__(256) void gn_kernel(
    const float* __restrict__ sol, const float* __restrict__ sev,
    const float* __restrict__ gnw, const float* __restrict__ gnb,
    float* __restrict__ y)
{
  __shared__ double red[256];
  const int n = blockIdx.x, tid = threadIdx.x;
  const float* sp = sol + (size_t)n * 9216;
  double s = 0.0;
  for (int i = tid; i < 9216; i += 256) s += (double)sp[i];
  red[tid] = s;
  __syncthreads();
  for (int st = 128; st > 0; st >>= 1) {
    if (tid < st) red[tid] += red[tid + st];
    __syncthreads();
  }
  const double mu = red[0] / 9216.0;
  __syncthreads();
  double s2 = 0.0;
  for (int i = tid; i < 9216; i += 256) {
    double dd = (double)sp[i] - mu;
    s2 += dd * dd;
  }
  red[tid] = s2;
  __syncthreads();
  for (int st = 128; st > 0; st >>= 1) {
    if (tid < st) red[tid] += red[tid + st];
    __syncthreads();
  }
  const double var = red[0] / 9216.0;
  const float rstd = (float)(1.0 / sqrt(var + 1e-5));
  const float muf = (float)mu;
  for (int i = tid; i < 9216; i += 256) {
    const int gg = i / 576;
    y[(size_t)n * 9216 + i] =
        ((sp[i] - muf) * rstd * gnw[gg] + gnb[gg]) * sev[n * 16 + gg];
  }
}

// ---------------------------------------------------------------------------
// post conv: (4,16,24,24) -> (4,128,24,24), 3x3 pad1.
// ---------------------------------------------------------------------------
__global__ __launch_bounds__(576) void post_kernel(
    const float* __restrict__ y, const float* __restrict__ w,
    const float* __restrict__ bias, float* __restrict__ out)
{
  __shared__ float sy[16 * 576];
  const int co = blockIdx.x, n = blockIdx.y, tid = threadIdx.x;
#pragma unroll
  for (int k = 0; k < 16; ++k)
    sy[k * 576 + tid] = y[(size_t)(n * 16 + k) * 576 + tid];
  __syncthreads();
  const int py = tid / 24, px = tid - py * 24;
  float acc = bias[co];
#pragma unroll 4
  for (int k = 0; k < 16; ++k) {
    const float* wp = w + (co * 16 + k) * 9;
#pragma unroll
    for (int dy = 0; dy < 3; ++dy) {
      const int yy = py + dy - 1;
      const bool oky = (unsigned)yy < 24u;
      const int iy = yy < 0 ? 0 : (yy > 23 ? 23 : yy);
#pragma unroll
      for (int dx = 0; dx < 3; ++dx) {
        const int xx = px + dx - 1;
        const bool ok = oky && ((unsigned)xx < 24u);
        const int ix = xx < 0 ? 0 : (xx > 23 ? 23 : xx);
        const float v = ok ? sy[k * 576 + iy * 24 + ix] : 0.f;
        acc += v * wp[dy * 3 + dx];
      }
    }
  }
  out[(size_t)(n * 128 + co) * 576 + tid] = acc;
}

// ---------------------------------------------------------------------------
extern "C" void kernel_launch(void* const* d_in, const int* in_sizes, int n_in,
                              void* d_out, int out_size, void* d_ws, size_t ws_size,
                              hipStream_t stream) {
  const float* x       = (const float*)d_in[0];
  const float* grad_w1 = (const float*)d_in[2];
  const float* grad_b1 = (const float*)d_in[3];
  const float* grad_w2 = (const float*)d_in[4];
  const float* grad_b2 = (const float*)d_in[5];
  const float* att_w1  = (const float*)d_in[6];
  const float* att_b1  = (const float*)d_in[7];
  const float* att_w2  = (const float*)d_in[8];
  const float* att_b2  = (const float*)d_in[9];
  const float* se_w1   = (const float*)d_in[10];
  const float* se_b1   = (const float*)d_in[11];
  const float* se_w2   = (const float*)d_in[12];
  const float* se_b2   = (const float*)d_in[13];
  const float* gn_w    = (const float*)d_in[14];
  const float* gn_b    = (const float*)d_in[15];
  const float* post_w  = (const float*)d_in[16];
  const float* post_b  = (const float*)d_in[17];
  float* out = (float*)d_out;

  float* ws  = (float*)d_ws;
  float* t1a = ws;              // 147456
  float* t1g = t1a + 147456;    // 147456
  float* att = t1g + 147456;    // 147456
  float* grd = att + 147456;    // 147456
  float* sev = grd + 147456;    // 64
  float* sol = sev + 64;        // 36864
  float* yb  = sol + 36864;     // 36864

  (void)hipFuncSetAttribute((const void*)chol_kernel,
                            hipFuncAttributeMaxDynamicSharedMemorySize,
                            (int)CHOL_LDS_BYTES);

  conv1_kernel<<<dim3(64, 4), 576, 0, stream>>>(x, att_w1, att_b1,
                                                grad_w1, grad_b1, t1a, t1g);
  se_kernel<<<4, 64, 0, stream>>>(x, se_w1, se_b1, se_w2, se_b2, sev);
  conv2_kernel<<<dim3(64, 4, 2), 576, 0, stream>>>(t1a, t1g, att_w2, att_b2,
                                                   grad_w2, grad_b2, att, grd);
  chol_kernel<<<64, CTH, CHOL_LDS_BYTES, stream>>>(att, grd, sol);
  gn_kernel<<<4, 256, 0, stream>>>(sol, sev, gn_w, gn_b, yb);
  post_kernel<<<dim3(128, 4), 576, 0, stream>>>(yb, post_w, post_b, out);
}

// Round 5
// 235.732 us; speedup vs baseline: 2.9495x; 1.1449x over previous
//
#include <hip/hip_runtime.h>
#include <math.h>

#define NUM 576
#define BSTR 50
#define CTH 256
// dynamic LDS: band (576*50) + 256-float dummy sink
#define CHOL_LDS_BYTES ((NUM * BSTR + CTH) * sizeof(float))

__device__ __forceinline__ float leakyf(float v) { return v > 0.f ? v : 0.01f * v; }
__device__ __forceinline__ float sigmoidf(float v) { return 1.f / (1.f + __expf(-v)); }
__device__ __forceinline__ float rdlane(float v, int l) {
  return __uint_as_float(__builtin_amdgcn_readlane(__float_as_uint(v), l));
}

// ---------------------------------------------------------------------------
// conv1: 3x3 pad1 conv on x (4,64,24,24) for BOTH branches, + leaky_relu.
// ---------------------------------------------------------------------------
__global__ __launch_bounds__(576) void conv1_kernel(
    const float* __restrict__ x,
    const float* __restrict__ wa, const float* __restrict__ ba,
    const float* __restrict__ wg, const float* __restrict__ bg,
    float* __restrict__ outa, float* __restrict__ outg)
{
  __shared__ float sx[16 * 576];
  const int co = blockIdx.x, n = blockIdx.y;
  const int tid = threadIdx.x;
  const int py = tid / 24, px = tid - py * 24;
  float acc_a = ba[co];
  float acc_g = bg[co];
  for (int c0 = 0; c0 < 64; c0 += 16) {
    __syncthreads();
#pragma unroll
    for (int k = 0; k < 16; ++k)
      sx[k * 576 + tid] = x[(n * 64 + c0 + k) * 576 + tid];
    __syncthreads();
#pragma unroll 4
    for (int k = 0; k < 16; ++k) {
      const float* wpa = wa + (co * 64 + c0 + k) * 9;
      const float* wpg = wg + (co * 64 + c0 + k) * 9;
#pragma unroll
      for (int dy = 0; dy < 3; ++dy) {
        const int yy = py + dy - 1;
        const bool oky = (unsigned)yy < 24u;
        const int iy = yy < 0 ? 0 : (yy > 23 ? 23 : yy);
#pragma unroll
        for (int dx = 0; dx < 3; ++dx) {
          const int xx = px + dx - 1;
          const bool ok = oky && ((unsigned)xx < 24u);
          const int ix = xx < 0 ? 0 : (xx > 23 ? 23 : xx);
          const float v = ok ? sx[k * 576 + iy * 24 + ix] : 0.f;
          acc_a += v * wpa[dy * 3 + dx];
          acc_g += v * wpg[dy * 3 + dx];
        }
      }
    }
  }
  const int o = (n * 64 + co) * 576 + tid;
  outa[o] = leakyf(acc_a);
  outg[o] = leakyf(acc_g);
}

// ---------------------------------------------------------------------------
// conv2: second 3x3 conv per branch. blockIdx.z selects branch.
// ---------------------------------------------------------------------------
__global__ __launch_bounds__(576) void conv2_kernel(
    const float* __restrict__ t1a, const float* __restrict__ t1g,
    const float* __restrict__ wa, const float* __restrict__ ba,
    const float* __restrict__ wg, const float* __restrict__ bg,
    float* __restrict__ att, float* __restrict__ grd)
{
  __shared__ float sx[16 * 576];
  const int co = blockIdx.x, n = blockIdx.y, br = blockIdx.z;
  const float* src = br ? t1g : t1a;
  const float* wp0 = br ? wg : wa;
  const float bias = br ? bg[co] : ba[co];
  float* dst = br ? grd : att;
  const int tid = threadIdx.x;
  const int py = tid / 24, px = tid - py * 24;
  float acc = bias;
  for (int c0 = 0; c0 < 64; c0 += 16) {
    __syncthreads();
#pragma unroll
    for (int k = 0; k < 16; ++k)
      sx[k * 576 + tid] = src[(n * 64 + c0 + k) * 576 + tid];
    __syncthreads();
#pragma unroll 4
    for (int k = 0; k < 16; ++k) {
      const float* wp = wp0 + (co * 64 + c0 + k) * 9;
#pragma unroll
      for (int dy = 0; dy < 3; ++dy) {
        const int yy = py + dy - 1;
        const bool oky = (unsigned)yy < 24u;
        const int iy = yy < 0 ? 0 : (yy > 23 ? 23 : yy);
#pragma unroll
        for (int dx = 0; dx < 3; ++dx) {
          const int xx = px + dx - 1;
          const bool ok = oky && ((unsigned)xx < 24u);
          const int ix = xx < 0 ? 0 : (xx > 23 ? 23 : xx);
          const float v = ok ? sx[k * 576 + iy * 24 + ix] : 0.f;
          acc += v * wp[dy * 3 + dx];
        }
      }
    }
  }
  if (br == 0) acc = sigmoidf(acc);
  dst[(n * 64 + co) * 576 + tid] = acc;
}

// ---------------------------------------------------------------------------
// SE branch.
// ---------------------------------------------------------------------------
__global__ __launch_bounds__(64) void se_kernel(
    const float* __restrict__ x,
    const float* __restrict__ w1, const float* __restrict__ b1,
    const float* __restrict__ w2, const float* __restrict__ b2,
    float* __restrict__ sev)
{
  __shared__ float pooled[64];
  __shared__ float hid[32];
  const int n = blockIdx.x, t = threadIdx.x;
  const float4* xp4 = (const float4*)(x + (size_t)(n * 64 + t) * 576);
  float s = 0.f;
  for (int p = 0; p < 144; ++p) {
    float4 v = xp4[p];
    s += v.x + v.y + v.z + v.w;
  }
  pooled[t] = s * (1.f / 576.f);
  __syncthreads();
  if (t < 32) {
    float h = b1[t];
    for (int c = 0; c < 64; ++c) h += pooled[c] * w1[t * 64 + c];
    hid[t] = leakyf(h);
  }
  __syncthreads();
  if (t < 16) {
    float v = b2[t];
    for (int j = 0; j < 32; ++j) v += hid[j] * w2[t * 32 + j];
    sev[n * 16 + t] = sigmoidf(v);
  }
}

// ---------------------------------------------------------------------------
// Fused banded Cholesky solver. 256 threads (4 waves) per system b = n*16+g.
// Rank-8 supersteps (72): wave-0 in-register 8-column micro-Cholesky with
// readlane broadcasts (VALU, not ds_bpermute) + fused forward substitution;
// rank-8 trailing update of the 1176-target triangle as 300 2x2 tiles with
// float2 column-panel reads. Back substitution: 72 rank-8 supersteps.
// Band: S[i*50+d] = A[i][i-d]; d=49 slots are never read (garbage-tolerant).
// ---------------------------------------------------------------------------
__global__ __launch_bounds__(CTH, 1) void chol_kernel(
    const float* __restrict__ att, const float* __restrict__ grd,
    float* __restrict__ sol)
{
  extern __shared__ float S[];          // [28800] band + [256] dummy sink
  __shared__ float RHS_s[NUM];
  __shared__ float RD_s[NUM];
  __shared__ float XS_s[NUM];
  __shared__ __align__(16) float CP[8][64];   // scaled panel columns
  __shared__ float DUMW[64];
  const int b = blockIdx.x, tid = threadIdx.x;
  const int n = b >> 4, g = b & 15;
  const float* ac = att + (size_t)(n * 64 + g * 4) * 576;
  const float* gc = grd + (size_t)(n * 64 + g * 4) * 576;

  // --- 2x2 tile decode: triangle (U,W), 0<=W<=U<=23, T = U(U+1)/2 + W.
  // Tile A: T = tid (tid<256<300, always valid when active-range allows).
  // Tile B: T = tid + 44 for tid >= 212 (covers 256..299).
  int r1A, r2A, r1B, r2B;
  bool tokB;
  {
    int T = tid;
    int U = (int)((sqrtf(8.f * (float)T + 1.f) - 1.f) * 0.5f);
    while (U * (U + 1) / 2 > T) --U;
    while ((U + 1) * (U + 2) / 2 <= T) ++U;
    int W = T - U * (U + 1) / 2;
    r1A = 8 + 2 * U; r2A = 8 + 2 * W;
    tokB = (tid >= 212);
    T = tokB ? (tid + 44) : 0;
    U = (int)((sqrtf(8.f * (float)T + 1.f) - 1.f) * 0.5f);
    while (U * (U + 1) / 2 > T) --U;
    while ((U + 1) * (U + 2) / 2 <= T) ++U;
    W = T - U * (U + 1) / 2;
    r1B = 8 + 2 * U; r2B = 8 + 2 * W;
  }

  // --- zero band
  for (int i = tid; i < NUM * BSTR; i += CTH) S[i] = 0.f;
  __syncthreads();

  // --- assemble band + rhs (verified math), seed rd[0]
  for (int i = tid; i < NUM; i += CTH) {
    float diag = 1e-12f, rv = 0.f;
    float od1 = 0.f, od2 = 0.f, od24 = 0.f, od48 = 0.f;
    if (((i + 1) % 24 != 0) && (i + 1 < NUM)) {
      float a0 = ac[0 * 576 + i]; float s = a0 * a0;
      diag += s; rv += s * gc[0 * 576 + i];
    }
    if (i - 1 >= 0 && (i % 24 != 0)) {
      float a0 = ac[0 * 576 + (i - 1)]; float s = a0 * a0;
      diag += s; rv -= s * gc[0 * 576 + (i - 1)]; od1 = -s;
    }
    if (i + 24 < NUM) {
      float a1 = ac[1 * 576 + i]; float s = a1 * a1;
      diag += s; rv += s * gc[1 * 576 + i];
    }
    if (i - 24 >= 0) {
      float a1 = ac[1 * 576 + (i - 24)]; float s = a1 * a1;
      diag += s; rv -= s * gc[1 * 576 + (i - 24)]; od24 = -s;
    }
    if (((i + 2) % 24 != 0) && (i + 2 < NUM)) {
      float a2 = ac[2 * 576 + i]; float s = a2 * a2;
      diag += s; rv += s * gc[2 * 576 + i];
    }
    if (i - 2 >= 0 && (i % 24 != 0)) {
      float a2 = ac[2 * 576 + (i - 2)]; float s = a2 * a2;
      diag += s; rv -= s * gc[2 * 576 + (i - 2)]; od2 = -s;
    }
    if (i + 48 < NUM) {
      float a3 = ac[3 * 576 + i]; float s = a3 * a3;
      diag += s; rv += s * gc[3 * 576 + i];
    }
    if (i - 48 >= 0) {
      float a3 = ac[3 * 576 + (i - 48)]; float s = a3 * a3;
      diag += s; rv -= s * gc[3 * 576 + (i - 48)]; od48 = -s;
    }
    if (i == NUM - 1) {
#pragma unroll
      for (int t = 0; t < 4; ++t) {
        float a = ac[t * 576 + (NUM - 1)]; float s = a * a;
        diag += s; rv += s * gc[t * 576 + (NUM - 1)];
      }
    }
    S[i * BSTR + 0] = diag;
    S[i * BSTR + 1] = od1;
    S[i * BSTR + 2] = od2;
    S[i * BSTR + 24] = od24;
    S[i * BSTR + 48] = od48;
    RHS_s[i] = rv;
    if (i == 0) RD_s[0] = rsqrtf(diag);
  }

  // --- factorization: 72 rank-8 supersteps
  for (int j = 0; j < NUM; j += 8) {
    __syncthreads();                       // prev update (or assemble) done
    // ---- scale phase: wave 0, in-register 8-col micro-Cholesky
    if (tid < 64) {
      const int t = tid;
      const int row = j + t;
      const bool rok = row < NUM;
      float v[8];
#pragma unroll
      for (int c = 0; c < 8; ++c) {
        const bool okc = rok && (t >= c) && (t - c <= 48);
        const int addr = okc ? (row * BSTR + (t - c)) : (NUM * BSTR + t);
        float vv = S[addr];
        v[c] = okc ? vv : 0.f;
      }
      float zb[8];
#pragma unroll
      for (int k = 0; k < 8; ++k) zb[k] = RHS_s[j + k];
      float z = S != nullptr ? RHS_s[rok ? row : j] : 0.f;
      z = rok ? z : 0.f;
      const float rd0 = RD_s[j];
      float rdv[8], y[8], lp[8][8];
#pragma unroll
      for (int k = 0; k < 8; ++k) {
        if (k == 0) {
          rdv[0] = rd0;
        } else {
          const float dk = rdlane(v[k], k);
          rdv[k] = rsqrtf(dk);
        }
        v[k] *= rdv[k];
#pragma unroll
        for (int m = k + 1; m < 8; ++m) {
          lp[m][k] = rdlane(v[k], m);
          v[m] -= v[k] * lp[m][k];
        }
      }
      // fused forward substitution (uniform scalars)
      y[0] = zb[0] * rdv[0];
#pragma unroll
      for (int k = 1; k < 8; ++k) {
        float acc = zb[k];
#pragma unroll
        for (int m = 0; m < 8; ++m)
          if (m < k) acc -= lp[k][m] * y[m];
        y[k] = acc * rdv[k];
      }
      float zn = z;
#pragma unroll
      for (int c = 0; c < 8; ++c) zn -= v[c] * y[c];
      // stores: scaled columns to band + CP panel
#pragma unroll
      for (int c = 0; c < 8; ++c) {
        const bool okc = rok && (t > c) && (t - c <= 48);
        float* bp = okc ? &S[row * BSTR + (t - c)] : &S[NUM * BSTR + t];
        *bp = v[c];
        CP[c][t] = okc ? v[c] : 0.f;
      }
      if (t < 8) {
        float yv = y[0], rv = rdv[0];
#pragma unroll
        for (int k = 1; k < 8; ++k) {
          yv = (t == k) ? y[k] : yv;
          rv = (t == k) ? rdv[k] : rv;
        }
        RHS_s[row] = yv;
        RD_s[row] = rv;
      } else {
        float* rp = rok ? &RHS_s[row] : &DUMW[t];
        *rp = zn;
      }
    }
    __syncthreads();                       // CP + columns visible
    // ---- rank-8 trailing update: 2x2 tiles
    const int R = (NUM - 1) - j;
    {
      // tile A
      const bool a0 = (r1A <= R);
      const bool a1 = (r1A + 1 <= R);
      float2 cr[8], cc[8];
#pragma unroll
      for (int c = 0; c < 8; ++c) {
        cr[c] = *(const float2*)&CP[c][r1A];
        cc[c] = *(const float2*)&CP[c][r2A];
      }
      float s00 = 0.f, s01 = 0.f, s10 = 0.f, s11 = 0.f;
#pragma unroll
      for (int c = 0; c < 8; ++c) {
        s00 += cr[c].x * cc[c].x; s01 += cr[c].x * cc[c].y;
        s10 += cr[c].y * cc[c].x; s11 += cr[c].y * cc[c].y;
      }
      const int p00 = j * BSTR + 51 * r1A - r2A;
      float* q00 = a0 ? &S[p00] : &S[NUM * BSTR + tid];
      float* q01 = a0 ? &S[p00 - 1] : &S[NUM * BSTR + tid];
      float* q10 = a1 ? &S[p00 + 51] : &S[NUM * BSTR + tid];
      float* q11 = a1 ? &S[p00 + 50] : &S[NUM * BSTR + tid];
      const float t00 = *q00 - s00, t01 = *q01 - s01;
      const float t10 = *q10 - s10, t11 = *q11 - s11;
      *q00 = t00; *q01 = t01; *q10 = t10; *q11 = t11;
      if (tid == 0 && a0)                  // tile (8,8): d_{j+8} final
        RD_s[j + 8] = rsqrtf(t00);
    }
    {
      // tile B (waves 3 only)
      const bool a0 = tokB && (r1B <= R);
      const bool a1 = tokB && (r1B + 1 <= R);
      float2 cr[8], cc[8];
#pragma unroll
      for (int c = 0; c < 8; ++c) {
        cr[c] = *(const float2*)&CP[c][r1B];
        cc[c] = *(const float2*)&CP[c][r2B];
      }
      float s00 = 0.f, s01 = 0.f, s10 = 0.f, s11 = 0.f;
#pragma unroll
      for (int c = 0; c < 8; ++c) {
        s00 += cr[c].x * cc[c].x; s01 += cr[c].x * cc[c].y;
        s10 += cr[c].y * cc[c].x; s11 += cr[c].y * cc[c].y;
      }
      const int p00 = j * BSTR + 51 * r1B - r2B;
      float* q00 = a0 ? &S[p00] : &S[NUM * BSTR + tid];
      float* q01 = a0 ? &S[p00 - 1] : &S[NUM * BSTR + tid];
      float* q10 = a1 ? &S[p00 + 51] : &S[NUM * BSTR + tid];
      float* q11 = a1 ? &S[p00 + 50] : &S[NUM * BSTR + tid];
      const float t00 = *q00 - s00, t01 = *q01 - s01;
      const float t10 = *q10 - s10, t11 = *q11 - s11;
      *q00 = t00; *q01 = t01; *q10 = t10; *q11 = t11;
    }
  }
  __syncthreads();

  // --- back substitution: 72 rank-8 supersteps, single wave
  if (tid < 64) {
    const int t = tid;
    for (int i = NUM - 1; i >= 7; i -= 8) {
      asm volatile("s_waitcnt lgkmcnt(0)" ::: "memory");
      float zz[8], rr[8];
#pragma unroll
      for (int k = 0; k < 8; ++k) { zz[k] = RHS_s[i - k]; rr[k] = RD_s[i - k]; }
      float L[8][8];
#pragma unroll
      for (int a = 0; a < 8; ++a)
#pragma unroll
        for (int bb = 0; bb < 8; ++bb)
          if (bb > a) L[a][bb] = S[(i - a) * BSTR + (bb - a)];
      float x[8];
      x[0] = zz[0] * rr[0];
#pragma unroll
      for (int k = 1; k < 8; ++k) {
        float acc = zz[k];
#pragma unroll
        for (int m = 0; m < 8; ++m)
          if (m < k) acc -= L[m][k] * x[m];
        x[k] = acc * rr[k];
      }
      // tail update: rows below the 8-block
      const int rb = i - 8 - t;
      const bool bok = rb >= 0;
      float acc2 = 0.f;
#pragma unroll
      for (int k = 0; k < 8; ++k) {
        const int d = 8 + t - k;
        const bool ok = bok && (d <= 48);
        float Lv = S[ok ? ((i - k) * BSTR + d) : (NUM * BSTR + t)];
        Lv = ok ? Lv : 0.f;
        acc2 += Lv * x[k];
      }
      const float zbv = RHS_s[bok ? rb : 0];
      float* rp = bok ? &RHS_s[rb] : &DUMW[t];
      *rp = zbv - acc2;
      float xv = x[0];
#pragma unroll
      for (int k = 1; k < 8; ++k) xv = (t == k) ? x[k] : xv;
      if (t < 8) XS_s[i - t] = xv;
    }
  }
  __syncthreads();
  for (int i = tid; i < NUM; i += CTH) sol[(size_t)b * NUM + i] = XS_s[i];
}

// ---------------------------------------------------------------------------
// GroupNorm(1, GR) + SE scale.
// ---------------------------------------------------------------------------
__global__ __launch_bounds__(256) void gn_kernel(
    const float* __restrict__ sol, const float* __restrict__ sev,
    const float* __restrict__ gnw, const float* __restrict__ gnb,
    float* __restrict__ y)
{
  __shared__ double red[256];
  const int n = blockIdx.x, tid = threadIdx.x;
  const float* sp = sol + (size_t)n * 9216;
  double s = 0.0;
  for (int i = tid; i < 9216; i += 256) s += (double)sp[i];
  red[tid] = s;
  __syncthreads();
  for (int st = 128; st > 0; st >>= 1) {
    if (tid < st) red[tid] += red[tid + st];
    __syncthreads();
  }
  const double mu = red[0] / 9216.0;
  __syncthreads();
  double s2 = 0.0;
  for (int i = tid; i < 9216; i += 256) {
    double dd = (double)sp[i] - mu;
    s2 += dd * dd;
  }
  red[tid] = s2;
  __syncthreads();
  for (int st = 128; st > 0; st >>= 1) {
    if (tid < st) red[tid] += red[tid + st];
    __syncthreads();
  }
  const double var = red[0] / 9216.0;
  const float rstd = (float)(1.0 / sqrt(var + 1e-5));
  const float muf = (float)mu;
  for (int i = tid; i < 9216; i += 256) {
    const int gg = i / 576;
    y[(size_t)n * 9216 + i] =
        ((sp[i] - muf) * rstd * gnw[gg] + gnb[gg]) * sev[n * 16 + gg];
  }
}

// ---------------------------------------------------------------------------
// post conv: (4,16,24,24) -> (4,128,24,24), 3x3 pad1.
// ---------------------------------------------------------------------------
__global__ __launch_bounds__(576) void post_kernel(
    const float* __restrict__ y, const float* __restrict__ w,
    const float* __restrict__ bias, float* __restrict__ out)
{
  __shared__ float sy[16 * 576];
  const int co = blockIdx.x, n = blockIdx.y, tid = threadIdx.x;
#pragma unroll
  for (int k = 0; k < 16; ++k)
    sy[k * 576 + tid] = y[(size_t)(n * 16 + k) * 576 + tid];
  __syncthreads();
  const int py = tid / 24, px = tid - py * 24;
  float acc = bias[co];
#pragma unroll 4
  for (int k = 0; k < 16; ++k) {
    const float* wp = w + (co * 16 + k) * 9;
#pragma unroll
    for (int dy = 0; dy < 3; ++dy) {
      const int yy = py + dy - 1;
      const bool oky = (unsigned)yy < 24u;
      const int iy = yy < 0 ? 0 : (yy > 23 ? 23 : yy);
#pragma unroll
      for (int dx = 0; dx < 3; ++dx) {
        const int xx = px + dx - 1;
        const bool ok = oky && ((unsigned)xx < 24u);
        const int ix = xx < 0 ? 0 : (xx > 23 ? 23 : xx);
        const float v = ok ? sy[k * 576 + iy * 24 + ix] : 0.f;
        acc += v * wp[dy * 3 + dx];
      }
    }
  }
  out[(size_t)(n * 128 + co) * 576 + tid] = acc;
}

// ---------------------------------------------------------------------------
extern "C" void kernel_launch(void* const* d_in, const int* in_sizes, int n_in,
                              void* d_out, int out_size, void* d_ws, size_t ws_size,
                              hipStream_t stream) {
  const float* x       = (const float*)d_in[0];
  const float* grad_w1 = (const float*)d_in[2];
  const float* grad_b1 = (const float*)d_in[3];
  const float* grad_w2 = (const float*)d_in[4];
  const float* grad_b2 = (const float*)d_in[5];
  const float* att_w1  = (const float*)d_in[6];
  const float* att_b1  = (const float*)d_in[7];
  const float* att_w2  = (const float*)d_in[8];
  const float* att_b2  = (const float*)d_in[9];
  const float* se_w1   = (const float*)d_in[10];
  const float* se_b1   = (const float*)d_in[11];
  const float* se_w2   = (const float*)d_in[12];
  const float* se_b2   = (const float*)d_in[13];
  const float* gn_w    = (const float*)d_in[14];
  const float* gn_b    = (const float*)d_in[15];
  const float* post_w  = (const float*)d_in[16];
  const float* post_b  = (const float*)d_in[17];
  float* out = (float*)d_out;

  float* ws  = (float*)d_ws;
  float* t1a = ws;              // 147456
  float* t1g = t1a + 147456;    // 147456
  float* att = t1g + 147456;    // 147456
  float* grd = att + 147456;    // 147456
  float* sev = grd + 147456;    // 64
  float* sol = sev + 64;        // 36864
  float* yb  = sol + 36864;     // 36864

  (void)hipFuncSetAttribute((const void*)chol_kernel,
                            hipFuncAttributeMaxDynamicSharedMemorySize,
                            (int)CHOL_LDS_BYTES);

  conv1_kernel<<<dim3(64, 4), 576, 0, stream>>>(x, att_w1, att_b1,
                                                grad_w1, grad_b1, t1a, t1g);
  se_kernel<<<4, 64, 0, stream>>>(x, se_w1, se_b1, se_w2, se_b2, sev);
  conv2_kernel<<<dim3(64, 4, 2), 576, 0, stream>>>(t1a, t1g, att_w2, att_b2,
                                                   grad_w2, grad_b2, att, grd);
  chol_kernel<<<64, CTH, CHOL_LDS_BYTES, stream>>>(att, grd, sol);
  gn_kernel<<<4, 256, 0, stream>>>(sol, sev, gn_w, gn_b, yb);
  post_kernel<<<dim3(128, 4), 576, 0, stream>>>(yb, post_w, post_b, out);
}